// Round 7
// baseline (1359.292 us; speedup 1.0000x reference)
//
#include <hip/hip_runtime.h>
#include <hip/hip_bf16.h>

// ---------------------------------------------------------------------------
// RGAT: 2x RGATConv (R=8, H=128) + mean/max pool + MLP head -> scalar
//
// R7 structure:
//   CSR build (2-level bucket sort, block-owned write windows)
//   per layer:
//     k_wprep: wqkb[16][128] = bf16(W@q|W@k)  +  WT2[h][r*128+k] (merged)
//     k_qkv<L0>: qkv[N][16] = xb @ wqkb^T (MFMA); L0 also emits xb=bf16(x)
//     k_agg2: 1 wave/node; online-softmax lane-parallel; 4-edge batches:
//             16 lanes x bf16x8 per edge, ds_bpermute weight broadcast,
//             LDS atomicAdd accumulate (collision-safe)
//     k_gemm: h = relu(agg[N,1024] @ Wcat[1024,128] + b)  (bf16 MFMA)
//   pool (mean+max) -> tanh -> fc1 relu -> fc2 -> sigmoid
//
// Record packing: rec = src | et<<17 | dlow<<20   (N < 2^17, dlow = dst&1023)
// ---------------------------------------------------------------------------

typedef __bf16 bf16x8 __attribute__((ext_vector_type(8)));
typedef __bf16 bf16x4 __attribute__((ext_vector_type(4)));
typedef __bf16 bf16x2 __attribute__((ext_vector_type(2)));
typedef float f32x4 __attribute__((ext_vector_type(4)));

#define CBSH 10                 // coarse bucket = 1024 nodes
#define CSC_CH 4096             // edges per cscatter block

// ----------------------------- CSR build -----------------------------------

__global__ __launch_bounds__(256) void k_chist(const int* __restrict__ dst, int* __restrict__ chist, int E) {
  __shared__ int lh[64];
  int t = threadIdx.x;
  if (t < 64) lh[t] = 0;
  __syncthreads();
  for (int e = blockIdx.x * 256 + t; e < E; e += gridDim.x * 256)
    atomicAdd(&lh[dst[e] >> CBSH], 1);
  __syncthreads();
  if (t < 64 && lh[t]) atomicAdd(&chist[t], lh[t]);
}

__global__ void k_cscan(const int* __restrict__ chist, int* __restrict__ cbase, int* __restrict__ ccur,
                        int ncb, int E) {
  if (threadIdx.x == 0) {
    int acc = 0;
    for (int i = 0; i < ncb; ++i) { cbase[i] = acc; ccur[i] = acc; acc += chist[i]; }
    cbase[ncb] = E;
  }
}

__global__ __launch_bounds__(256) void k_cscatter(const int* __restrict__ src, const int* __restrict__ dst,
                                                  const int* __restrict__ et, int* __restrict__ ccur,
                                                  int* __restrict__ tmp, int E) {
  __shared__ int recbuf[CSC_CH];
  __shared__ int lcnt[64], lbase[64], gbase[64], lcur[64];
  int t = threadIdx.x;
  int base = blockIdx.x * CSC_CH;
  int cnt = E - base; if (cnt > CSC_CH) cnt = CSC_CH;
  if (t < 64) lcnt[t] = 0;
  __syncthreads();
  int myrec[CSC_CH / 256], mycb[CSC_CH / 256];
  int k = 0;
  for (int i = t; i < cnt; i += 256, ++k) {
    int d = dst[base + i];
    int cb = d >> CBSH;
    myrec[k] = src[base + i] | (et[base + i] << 17) | ((d & ((1 << CBSH) - 1)) << 20);
    mycb[k] = cb;
    atomicAdd(&lcnt[cb], 1);
  }
  __syncthreads();
  if (t == 0) {
    int acc = 0;
    for (int c = 0; c < 64; ++c) { lbase[c] = acc; lcur[c] = acc; acc += lcnt[c]; }
  }
  __syncthreads();
  if (t < 64 && lcnt[t] > 0) gbase[t] = atomicAdd(&ccur[t], lcnt[t]);
  __syncthreads();
  k = 0;
  for (int i = t; i < cnt; i += 256, ++k) {
    int p = atomicAdd(&lcur[mycb[k]], 1);
    recbuf[p] = myrec[k];
  }
  __syncthreads();
  for (int i = t; i < cnt; i += 256) {
    int lo = 0, hi = 63;
    while (lo < hi) { int mid = (lo + hi + 1) >> 1; if (lbase[mid] <= i) lo = mid; else hi = mid - 1; }
    tmp[gbase[lo] + (i - lbase[lo])] = recbuf[i];
  }
}

__global__ __launch_bounds__(1024) void k_fsort(const int* __restrict__ cbase, const int* __restrict__ tmp,
                                                int* __restrict__ recs, int* __restrict__ row_ptr,
                                                int N, int E) {
  __shared__ int sd[1024];
  __shared__ int ncur[1024];
  int cb = blockIdx.x, t = threadIdx.x;
  int n0 = cb << CBSH;
  int begin = cbase[cb], endd = cbase[cb + 1];
  sd[t] = 0;
  __syncthreads();
  for (int i = begin + t; i < endd; i += 1024)
    atomicAdd(&sd[(tmp[i] >> 20) & 1023], 1);
  __syncthreads();
  int myc = sd[t];
  for (int off = 1; off < 1024; off <<= 1) {
    int xv = 0; if (t >= off) xv = sd[t - off];
    __syncthreads();
    sd[t] += xv;
    __syncthreads();
  }
  int ex = sd[t] - myc;
  int node = n0 + t;
  if (node < N) row_ptr[node] = begin + ex;
  if (node == N - 1) row_ptr[N] = E;
  ncur[t] = begin + ex;
  __syncthreads();
  for (int i = begin + t; i < endd; i += 1024) {
    int rc = tmp[i];
    int p = atomicAdd(&ncur[(rc >> 20) & 1023], 1);
    recs[p] = rc & 0xFFFFF;                        // src | et<<17
  }
}

// ----------------------- merged weight precompute ----------------------------
// blocks 0..255: wqkb rows; blocks 256..383: WT2 transpose tiles.

__global__ __launch_bounds__(256) void k_wprep(const float* __restrict__ W, const float* __restrict__ q,
                                               const float* __restrict__ k, __bf16* __restrict__ wqkb,
                                               __bf16* __restrict__ WT) {
  if (blockIdx.x < 256) {
    int g = blockIdx.x * 4 + (threadIdx.x >> 6);
    int lane = threadIdx.x & 63;
    const float2* wrow = (const float2*)(W + (size_t)g * 128);
    float2 wv = wrow[lane];
    float2 qv2 = ((const float2*)q)[lane];
    float2 kv2 = ((const float2*)k)[lane];
    float aq = wv.x * qv2.x + wv.y * qv2.y;
    float ak = wv.x * kv2.x + wv.y * kv2.y;
    #pragma unroll
    for (int off = 32; off; off >>= 1) {
      aq += __shfl_xor(aq, off, 64);
      ak += __shfl_xor(ak, off, 64);
    }
    if (lane == 0) { wqkb[g] = (__bf16)aq; wqkb[1024 + g] = (__bf16)ak; }
  } else {
    __shared__ float t[32][33];
    int bb = blockIdx.x - 256;
    int r = bb >> 4;
    int rem = bb & 15;
    int k0 = (rem & 3) * 32, h0 = (rem >> 2) * 32;
    int tx = threadIdx.x & 31;
    int ty = threadIdx.x >> 5;
    #pragma unroll
    for (int i = 0; i < 4; ++i) {
      int kk = ty + i * 8;
      t[kk][tx] = W[((size_t)r * 128 + k0 + kk) * 128 + h0 + tx];
    }
    __syncthreads();
    #pragma unroll
    for (int i = 0; i < 4; ++i) {
      int hh = ty + i * 8;
      WT[(size_t)(h0 + hh) * 1024 + r * 128 + k0 + tx] = (__bf16)t[tx][hh];
    }
  }
}

// qkv[n][c] = xin[n]·wqkb[c]; L0 variant reads f32 x and emits xb = bf16(x).
template <int L0>
__global__ __launch_bounds__(256) void k_qkv(const void* __restrict__ xin, const __bf16* __restrict__ wqkb,
                                             float* __restrict__ qkv, __bf16* __restrict__ xbout, int N) {
  int wv = threadIdx.x >> 6, l = threadIdx.x & 63;
  int nb = blockIdx.x * 64 + wv * 16;
  if (nb >= N) return;
  int arow = nb + (l & 15);
  bool valid = arow < N;
  int koff = (l >> 4) * 8;
  const bf16x8* gB = (const bf16x8*)(wqkb + (size_t)(l & 15) * 128 + koff);
  f32x4 acc = (f32x4)0.f;
  #pragma unroll
  for (int kt = 0; kt < 4; ++kt) {
    bf16x8 bv = gB[kt * 4];
    bf16x8 av;
    if (L0) {
      const float* gA = (const float*)xin + (size_t)arow * 128 + koff + kt * 32;
      float4 f0 = make_float4(0.f, 0.f, 0.f, 0.f), f1 = f0;
      if (valid) { f0 = *(const float4*)gA; f1 = *(const float4*)(gA + 4); }
      av[0] = (__bf16)f0.x; av[1] = (__bf16)f0.y; av[2] = (__bf16)f0.z; av[3] = (__bf16)f0.w;
      av[4] = (__bf16)f1.x; av[5] = (__bf16)f1.y; av[6] = (__bf16)f1.z; av[7] = (__bf16)f1.w;
      if (valid) *(bf16x8*)(xbout + (size_t)arow * 128 + koff + kt * 32) = av;
    } else {
      const bf16x8* gA = (const bf16x8*)((const __bf16*)xin + (size_t)arow * 128 + koff);
      av = valid ? gA[kt * 4] : (bf16x8)(__bf16)0.0f;
    }
    acc = __builtin_amdgcn_mfma_f32_16x16x32_bf16(av, bv, acc, 0, 0, 0);
  }
  #pragma unroll
  for (int j = 0; j < 4; ++j) {
    int row = nb + (l >> 4) * 4 + j;
    if (row < N) qkv[(size_t)row * 16 + (l & 15)] = acc[j];
  }
}

// ------------------- softmax + gather aggregate (to agg) ---------------------
// One wave per node; LDS row accumulator [1024] f32 per wave.
// 4-edge batches: 16 lanes x bf16x8 per edge; ds_bpermute broadcasts the
// edge record + weight to each lane group; LDS atomicAdd handles relation
// collisions within a batch.

__global__ __launch_bounds__(256) void k_agg2(const int* __restrict__ row_ptr, const int* __restrict__ recs,
                                              const float* __restrict__ qkv, const __bf16* __restrict__ xb,
                                              __bf16* __restrict__ agg, int N) {
  __shared__ float lacc[4][1024];
  int wv = threadIdx.x >> 6;
  int lane = threadIdx.x & 63;
  int n = blockIdx.x * 4 + wv;
  if (n >= N) return;
  float* A = lacc[wv];
  float4* A4 = (float4*)A;
  #pragma unroll
  for (int i = 0; i < 4; ++i) A4[lane + i * 64] = make_float4(0.f, 0.f, 0.f, 0.f);
  // per-wave private region; same-wave LDS ops are ordered -> no barrier.

  int start = row_ptr[n], end = row_ptr[n + 1];
  const float* qvn = qkv + (size_t)n * 16;
  float denom = 0.f, m_run = -1e30f;
  int sub = lane & 15;
  int permbase = (lane >> 4) * 4;        // bpermute byte index base

  for (int c0 = start; c0 < end; c0 += 64) {
    int cend = (end < c0 + 64) ? end : (c0 + 64);
    int cnt = cend - c0;
    int p = c0 + lane;
    float a = -1e30f; int rec = 0;
    if (p < cend) {
      rec = recs[p];
      int s = rec & 0x1FFFF, r = (rec >> 17) & 7;
      float t = qvn[r] + qkv[(size_t)s * 16 + 8 + r];
      a = (t >= 0.f) ? t : 0.2f * t;
    }
    float cm = a;
    #pragma unroll
    for (int off = 32; off; off >>= 1) cm = fmaxf(cm, __shfl_xor(cm, off, 64));
    if (cm > m_run) {
      if (m_run > -1e29f) {
        float scale = __expf(m_run - cm);
        denom *= scale;
        #pragma unroll
        for (int i = 0; i < 4; ++i) {
          float4 c = A4[lane + i * 64];
          c.x *= scale; c.y *= scale; c.z *= scale; c.w *= scale;
          A4[lane + i * 64] = c;
        }
      }
      m_run = cm;
    }
    float wgt = (p < cend) ? __expf(a - m_run) : 0.f;
    float ws = wgt;
    #pragma unroll
    for (int off = 32; off; off >>= 1) ws += __shfl_xor(ws, off, 64);
    denom += ws;
    int wbits = __float_as_int(wgt);

    int nbatch = (cnt + 3) >> 2;
    #pragma unroll 2
    for (int b = 0; b < nbatch; ++b) {
      int idx = permbase + b * 16;
      int rg = __builtin_amdgcn_ds_bpermute(idx, rec);     // group's edge record
      int wg = __builtin_amdgcn_ds_bpermute(idx, wbits);   // group's weight
      float fw = __int_as_float(wg);
      int s_ = rg & 0x1FFFF;
      int r_ = (rg >> 17) & 7;
      bf16x8 xv = *(const bf16x8*)(xb + (size_t)s_ * 128 + sub * 8);
      float* ap = &A[r_ * 128 + sub * 8];
      #pragma unroll
      for (int j = 0; j < 8; ++j) atomicAdd(&ap[j], fw * (float)xv[j]);
    }
  }

  float inv = 1.f / (denom + 1e-16f);
  __bf16* ag = agg + (size_t)n * 1024;
  #pragma unroll
  for (int i = 0; i < 4; ++i) {
    float4 c = A4[lane + i * 64];
    bf16x4 o;
    o.x = (__bf16)(c.x * inv); o.y = (__bf16)(c.y * inv);
    o.z = (__bf16)(c.z * inv); o.w = (__bf16)(c.w * inv);
    *(bf16x4*)(ag + (size_t)(lane + i * 64) * 4) = o;
  }
}

// --------------------------- MFMA GEMM (K=1024) ------------------------------

#define LSTR 72

__global__ __launch_bounds__(256) void k_gemm(const __bf16* __restrict__ A, const __bf16* __restrict__ B,
                                              const float* __restrict__ bias, __bf16* __restrict__ C, int M) {
  __shared__ __bf16 As[128 * LSTR];
  __shared__ __bf16 Bs[128 * LSTR];
  int bm = blockIdx.x * 128;
  int tid = threadIdx.x;
  int w = tid >> 6, l = tid & 63;

  f32x4 acc[2][8];
  #pragma unroll
  for (int m2 = 0; m2 < 2; ++m2)
    #pragma unroll
    for (int n2 = 0; n2 < 8; ++n2) acc[m2][n2] = (f32x4)0.f;

  int srow = tid >> 1;
  int cbase = (tid & 1) * 4;
  bool valid = (bm + srow) < M;
  const bf16x8* gA = (const bf16x8*)(A + (size_t)(bm + srow) * 1024);
  const bf16x8* gB = (const bf16x8*)(B + (size_t)srow * 1024);

  bf16x8 av[4], bv[4];
  #pragma unroll
  for (int i = 0; i < 4; ++i) {
    av[i] = valid ? gA[cbase + i] : (bf16x8)(__bf16)0.0f;
    bv[i] = gB[cbase + i];
  }

  for (int kt = 0; kt < 16; ++kt) {
    if (kt) __syncthreads();
    #pragma unroll
    for (int i = 0; i < 4; ++i) {
      *(bf16x8*)&As[srow * LSTR + (cbase + i) * 8] = av[i];
      *(bf16x8*)&Bs[srow * LSTR + (cbase + i) * 8] = bv[i];
    }
    __syncthreads();
    if (kt < 15) {
      #pragma unroll
      for (int i = 0; i < 4; ++i) {
        av[i] = valid ? gA[(kt + 1) * 8 + cbase + i] : (bf16x8)(__bf16)0.0f;
        bv[i] = gB[(kt + 1) * 8 + cbase + i];
      }
    }
    #pragma unroll
    for (int ks = 0; ks < 2; ++ks) {
      bf16x8 af[2], bfv[8];
      #pragma unroll
      for (int m2 = 0; m2 < 2; ++m2)
        af[m2] = *(const bf16x8*)&As[(w * 32 + m2 * 16 + (l & 15)) * LSTR + ks * 32 + (l >> 4) * 8];
      #pragma unroll
      for (int n2 = 0; n2 < 8; ++n2)
        bfv[n2] = *(const bf16x8*)&Bs[(n2 * 16 + (l & 15)) * LSTR + ks * 32 + (l >> 4) * 8];
      #pragma unroll
      for (int m2 = 0; m2 < 2; ++m2)
        #pragma unroll
        for (int n2 = 0; n2 < 8; ++n2)
          acc[m2][n2] = __builtin_amdgcn_mfma_f32_16x16x32_bf16(af[m2], bfv[n2], acc[m2][n2], 0, 0, 0);
    }
  }

  #pragma unroll
  for (int m2 = 0; m2 < 2; ++m2)
    #pragma unroll
    for (int j = 0; j < 4; ++j) {
      int row = w * 32 + m2 * 16 + (l >> 4) * 4 + j;
      if (bm + row < M) {
        #pragma unroll
        for (int n2 = 0; n2 < 8; ++n2) {
          float v = acc[m2][n2][j] + bias[n2 * 16 + (l & 15)];
          v = v > 0.f ? v : 0.f;
          C[(size_t)(bm + row) * 128 + n2 * 16 + (l & 15)] = (__bf16)v;
        }
      }
    }
}

// ------------------------------- pool + head ---------------------------------

__global__ __launch_bounds__(256) void k_pool(const __bf16* __restrict__ h, float* __restrict__ gsum,
                                              float* __restrict__ gmax, int N) {
  int c2 = threadIdx.x & 63;
  int grp = threadIdx.x >> 6;
  float s0 = 0.f, s1 = 0.f, m0 = 0.f, m1 = 0.f;
  for (int n = blockIdx.x * 4 + grp; n < N; n += gridDim.x * 4) {
    bf16x2 v = ((const bf16x2*)(h + (size_t)n * 128))[c2];
    float v0 = (float)v.x, v1 = (float)v.y;
    s0 += v0; s1 += v1;
    m0 = fmaxf(m0, v0); m1 = fmaxf(m1, v1);
  }
  __shared__ float ss0[256], ss1[256], sm0[256], sm1[256];
  ss0[threadIdx.x] = s0; ss1[threadIdx.x] = s1;
  sm0[threadIdx.x] = m0; sm1[threadIdx.x] = m1;
  __syncthreads();
  if (grp == 0) {
    #pragma unroll
    for (int g = 1; g < 4; ++g) {
      s0 += ss0[g * 64 + c2]; s1 += ss1[g * 64 + c2];
      m0 = fmaxf(m0, sm0[g * 64 + c2]); m1 = fmaxf(m1, sm1[g * 64 + c2]);
    }
    atomicAdd(&gsum[2 * c2 + 0], s0);
    atomicAdd(&gsum[2 * c2 + 1], s1);
    atomicMax((int*)gmax + 2 * c2 + 0, __float_as_int(m0));
    atomicMax((int*)gmax + 2 * c2 + 1, __float_as_int(m1));
  }
}

__global__ void k_head(const float* __restrict__ gsum, const float* __restrict__ gmax,
                       const float* __restrict__ fc1w, const float* __restrict__ fc1b,
                       const float* __restrict__ fc2w, const float* __restrict__ fc2b,
                       float* __restrict__ out, int N) {
  __shared__ float g[256];
  __shared__ float red[128];
  int t = threadIdx.x;
  if (t < 128) g[t] = tanhf(gsum[t] / (float)N);
  else g[t] = tanhf(gmax[t - 128]);
  __syncthreads();
  float r1 = 0.f;
  if (t < 128) {
    float a = fc1b[t];
    for (int i = 0; i < 256; i++) a += g[i] * fc1w[i * 128 + t];
    r1 = a > 0.f ? a : 0.f;
    red[t] = r1 * fc2w[t];
  }
  __syncthreads();
  for (int s = 64; s > 0; s >>= 1) {
    if (t < s) red[t] += red[t + s];
    __syncthreads();
  }
  if (t == 0) {
    float o = red[0] + fc2b[0];
    out[0] = 1.f / (1.f + __expf(-o));
  }
}

// --------------------------------- launch ------------------------------------

extern "C" void kernel_launch(void* const* d_in, const int* in_sizes, int n_in,
                              void* d_out, int out_size, void* d_ws, size_t ws_size,
                              hipStream_t stream) {
  const float* x    = (const float*)d_in[0];
  const int*   ei   = (const int*)d_in[1];
  const int*   ety  = (const int*)d_in[2];
  const float* w0   = (const float*)d_in[3];
  const float* q0   = (const float*)d_in[4];
  const float* k0   = (const float*)d_in[5];
  const float* b0   = (const float*)d_in[6];
  const float* w1   = (const float*)d_in[7];
  const float* q1   = (const float*)d_in[8];
  const float* k1   = (const float*)d_in[9];
  const float* b1   = (const float*)d_in[10];
  const float* fc1w = (const float*)d_in[11];
  const float* fc1b = (const float*)d_in[12];
  const float* fc2w = (const float*)d_in[13];
  const float* fc2b = (const float*)d_in[14];
  int N = in_sizes[0] / 128;
  int E = in_sizes[2];
  const int* src = ei;
  const int* dst = ei + E;

  char* base = (char*)d_ws;
  size_t off = 0;
  auto alloc = [&](size_t bytes) -> void* {
    off = (off + 255) & ~(size_t)255;
    void* p = base + off;
    off += bytes;
    return p;
  };
  int ncb = (N + (1 << CBSH) - 1) >> CBSH;

  int*    row_ptr = (int*)alloc((size_t)(N + 1) * 4);
  int*    chist   = (int*)alloc(64 * 4);
  int*    cbase   = (int*)alloc(65 * 4);
  int*    ccur    = (int*)alloc(64 * 4);
  int*    tmp     = (int*)alloc((size_t)E * 4);
  int*    recs    = (int*)alloc((size_t)E * 4);
  float*  qkv     = (float*)alloc((size_t)N * 16 * 4);
  float*  gsum    = (float*)alloc(128 * 4);
  float*  gmax    = (float*)alloc(128 * 4);
  __bf16* wqkb    = (__bf16*)alloc(2048 * 2);
  __bf16* xb      = (__bf16*)alloc((size_t)N * 128 * 2);
  __bf16* h1b     = (__bf16*)alloc((size_t)N * 128 * 2);
  __bf16* h2b     = (__bf16*)alloc((size_t)N * 128 * 2);
  __bf16* WT2     = (__bf16*)alloc((size_t)128 * 1024 * 2);
  __bf16* agg     = (__bf16*)alloc((size_t)N * 1024 * 2);

  // CSR build
  hipMemsetAsync(chist, 0, 64 * 4, stream);
  k_chist<<<256, 256, 0, stream>>>(dst, chist, E);
  k_cscan<<<1, 64, 0, stream>>>(chist, cbase, ccur, ncb, E);
  k_cscatter<<<(E + CSC_CH - 1) / CSC_CH, 256, 0, stream>>>(src, dst, ety, ccur, tmp, E);
  k_fsort<<<ncb, 1024, 0, stream>>>(cbase, tmp, recs, row_ptr, N, E);

  for (int layer = 0; layer < 2; ++layer) {
    const float*  W    = layer ? w1 : w0;
    const float*  qq   = layer ? q1 : q0;
    const float*  kk   = layer ? k1 : k0;
    const float*  bb   = layer ? b1 : b0;
    const __bf16* xinb = layer ? h1b : xb;
    __bf16*       hout = layer ? h2b : h1b;

    k_wprep<<<384, 256, 0, stream>>>(W, qq, kk, wqkb, WT2);
    if (layer == 0)
      k_qkv<1><<<(N + 63) / 64, 256, 0, stream>>>((const void*)x, wqkb, qkv, xb, N);
    else
      k_qkv<0><<<(N + 63) / 64, 256, 0, stream>>>((const void*)xinb, wqkb, qkv, nullptr, N);
    k_agg2<<<(N + 3) / 4, 256, 0, stream>>>(row_ptr, recs, qkv, xinb, agg, N);
    k_gemm<<<(N + 127) / 128, 256, 0, stream>>>(agg, WT2, bb, hout, N);
  }

  hipMemsetAsync(gsum, 0, 128 * 4, stream);
  hipMemsetAsync(gmax, 0, 128 * 4, stream);
  k_pool<<<256, 256, 0, stream>>>(h2b, gsum, gmax, N);
  k_head<<<1, 256, 0, stream>>>(gsum, gmax, fc1w, fc1b, fc2w, fc2b, (float*)d_out, N);
}

// Round 8
// 288.857 us; speedup vs baseline: 4.7058x; 4.7058x over previous
//
#include <hip/hip_runtime.h>
#include <hip/hip_bf16.h>

// ---------------------------------------------------------------------------
// RGAT: 2x RGATConv (R=8, H=128) + mean/max pool + MLP head -> scalar
//
// R8 structure:
//   CSR build (2-level bucket sort, block-owned write windows)
//   per layer:
//     k_wprep: wqkb[16][128] = bf16(W@q|W@k)  +  WT2[h][r*128+k] (merged)
//     k_qkv<L0>: qkv[N][16] = xb @ wqkb^T (MFMA); L0 also emits xb=bf16(x)
//     k_agg2: 1 wave/node; online-softmax lane-parallel; 4-edge batches:
//             16 lanes x bf16x8 per edge (1 dwordx4 insn = 4 rows),
//             ds_bpermute weight broadcast, RMW via 4 exec-mask-serialized
//             group steps (plain LDS float4 ops, NO atomics -- R7 lesson)
//     k_gemm: h = relu(agg[N,1024] @ Wcat[1024,128] + b)  (bf16 MFMA)
//   pool (mean+max) -> tanh -> fc1 relu -> fc2 -> sigmoid
//
// Record packing: rec = src | et<<17 | dlow<<20   (N < 2^17, dlow = dst&1023)
// ---------------------------------------------------------------------------

typedef __bf16 bf16x8 __attribute__((ext_vector_type(8)));
typedef __bf16 bf16x4 __attribute__((ext_vector_type(4)));
typedef __bf16 bf16x2 __attribute__((ext_vector_type(2)));
typedef float f32x4 __attribute__((ext_vector_type(4)));

#define CBSH 10                 // coarse bucket = 1024 nodes
#define CSC_CH 4096             // edges per cscatter block

// ----------------------------- CSR build -----------------------------------

__global__ __launch_bounds__(256) void k_chist(const int* __restrict__ dst, int* __restrict__ chist, int E) {
  __shared__ int lh[64];
  int t = threadIdx.x;
  if (t < 64) lh[t] = 0;
  __syncthreads();
  for (int e = blockIdx.x * 256 + t; e < E; e += gridDim.x * 256)
    atomicAdd(&lh[dst[e] >> CBSH], 1);
  __syncthreads();
  if (t < 64 && lh[t]) atomicAdd(&chist[t], lh[t]);
}

__global__ void k_cscan(const int* __restrict__ chist, int* __restrict__ cbase, int* __restrict__ ccur,
                        int ncb, int E) {
  if (threadIdx.x == 0) {
    int acc = 0;
    for (int i = 0; i < ncb; ++i) { cbase[i] = acc; ccur[i] = acc; acc += chist[i]; }
    cbase[ncb] = E;
  }
}

__global__ __launch_bounds__(256) void k_cscatter(const int* __restrict__ src, const int* __restrict__ dst,
                                                  const int* __restrict__ et, int* __restrict__ ccur,
                                                  int* __restrict__ tmp, int E) {
  __shared__ int recbuf[CSC_CH];
  __shared__ int lcnt[64], lbase[64], gbase[64], lcur[64];
  int t = threadIdx.x;
  int base = blockIdx.x * CSC_CH;
  int cnt = E - base; if (cnt > CSC_CH) cnt = CSC_CH;
  if (t < 64) lcnt[t] = 0;
  __syncthreads();
  int myrec[CSC_CH / 256], mycb[CSC_CH / 256];
  int k = 0;
  for (int i = t; i < cnt; i += 256, ++k) {
    int d = dst[base + i];
    int cb = d >> CBSH;
    myrec[k] = src[base + i] | (et[base + i] << 17) | ((d & ((1 << CBSH) - 1)) << 20);
    mycb[k] = cb;
    atomicAdd(&lcnt[cb], 1);
  }
  __syncthreads();
  if (t == 0) {
    int acc = 0;
    for (int c = 0; c < 64; ++c) { lbase[c] = acc; lcur[c] = acc; acc += lcnt[c]; }
  }
  __syncthreads();
  if (t < 64 && lcnt[t] > 0) gbase[t] = atomicAdd(&ccur[t], lcnt[t]);
  __syncthreads();
  k = 0;
  for (int i = t; i < cnt; i += 256, ++k) {
    int p = atomicAdd(&lcur[mycb[k]], 1);
    recbuf[p] = myrec[k];
  }
  __syncthreads();
  for (int i = t; i < cnt; i += 256) {
    int lo = 0, hi = 63;
    while (lo < hi) { int mid = (lo + hi + 1) >> 1; if (lbase[mid] <= i) lo = mid; else hi = mid - 1; }
    tmp[gbase[lo] + (i - lbase[lo])] = recbuf[i];
  }
}

__global__ __launch_bounds__(1024) void k_fsort(const int* __restrict__ cbase, const int* __restrict__ tmp,
                                                int* __restrict__ recs, int* __restrict__ row_ptr,
                                                int N, int E) {
  __shared__ int sd[1024];
  __shared__ int ncur[1024];
  int cb = blockIdx.x, t = threadIdx.x;
  int n0 = cb << CBSH;
  int begin = cbase[cb], endd = cbase[cb + 1];
  sd[t] = 0;
  __syncthreads();
  for (int i = begin + t; i < endd; i += 1024)
    atomicAdd(&sd[(tmp[i] >> 20) & 1023], 1);
  __syncthreads();
  int myc = sd[t];
  for (int off = 1; off < 1024; off <<= 1) {
    int xv = 0; if (t >= off) xv = sd[t - off];
    __syncthreads();
    sd[t] += xv;
    __syncthreads();
  }
  int ex = sd[t] - myc;
  int node = n0 + t;
  if (node < N) row_ptr[node] = begin + ex;
  if (node == N - 1) row_ptr[N] = E;
  ncur[t] = begin + ex;
  __syncthreads();
  for (int i = begin + t; i < endd; i += 1024) {
    int rc = tmp[i];
    int p = atomicAdd(&ncur[(rc >> 20) & 1023], 1);
    recs[p] = rc & 0xFFFFF;                        // src | et<<17
  }
}

// ----------------------- merged weight precompute ----------------------------

__global__ __launch_bounds__(256) void k_wprep(const float* __restrict__ W, const float* __restrict__ q,
                                               const float* __restrict__ k, __bf16* __restrict__ wqkb,
                                               __bf16* __restrict__ WT) {
  if (blockIdx.x < 256) {
    int g = blockIdx.x * 4 + (threadIdx.x >> 6);
    int lane = threadIdx.x & 63;
    const float2* wrow = (const float2*)(W + (size_t)g * 128);
    float2 wv = wrow[lane];
    float2 qv2 = ((const float2*)q)[lane];
    float2 kv2 = ((const float2*)k)[lane];
    float aq = wv.x * qv2.x + wv.y * qv2.y;
    float ak = wv.x * kv2.x + wv.y * kv2.y;
    #pragma unroll
    for (int off = 32; off; off >>= 1) {
      aq += __shfl_xor(aq, off, 64);
      ak += __shfl_xor(ak, off, 64);
    }
    if (lane == 0) { wqkb[g] = (__bf16)aq; wqkb[1024 + g] = (__bf16)ak; }
  } else {
    __shared__ float t[32][33];
    int bb = blockIdx.x - 256;
    int r = bb >> 4;
    int rem = bb & 15;
    int k0 = (rem & 3) * 32, h0 = (rem >> 2) * 32;
    int tx = threadIdx.x & 31;
    int ty = threadIdx.x >> 5;
    #pragma unroll
    for (int i = 0; i < 4; ++i) {
      int kk = ty + i * 8;
      t[kk][tx] = W[((size_t)r * 128 + k0 + kk) * 128 + h0 + tx];
    }
    __syncthreads();
    #pragma unroll
    for (int i = 0; i < 4; ++i) {
      int hh = ty + i * 8;
      WT[(size_t)(h0 + hh) * 1024 + r * 128 + k0 + tx] = (__bf16)t[tx][hh];
    }
  }
}

// qkv[n][c] = xin[n]·wqkb[c]; L0 variant reads f32 x and emits xb = bf16(x).
template <int L0>
__global__ __launch_bounds__(256) void k_qkv(const void* __restrict__ xin, const __bf16* __restrict__ wqkb,
                                             float* __restrict__ qkv, __bf16* __restrict__ xbout, int N) {
  int wv = threadIdx.x >> 6, l = threadIdx.x & 63;
  int nb = blockIdx.x * 64 + wv * 16;
  if (nb >= N) return;
  int arow = nb + (l & 15);
  bool valid = arow < N;
  int koff = (l >> 4) * 8;
  const bf16x8* gB = (const bf16x8*)(wqkb + (size_t)(l & 15) * 128 + koff);
  f32x4 acc = (f32x4)0.f;
  #pragma unroll
  for (int kt = 0; kt < 4; ++kt) {
    bf16x8 bv = gB[kt * 4];
    bf16x8 av;
    if (L0) {
      const float* gA = (const float*)xin + (size_t)arow * 128 + koff + kt * 32;
      float4 f0 = make_float4(0.f, 0.f, 0.f, 0.f), f1 = f0;
      if (valid) { f0 = *(const float4*)gA; f1 = *(const float4*)(gA + 4); }
      av[0] = (__bf16)f0.x; av[1] = (__bf16)f0.y; av[2] = (__bf16)f0.z; av[3] = (__bf16)f0.w;
      av[4] = (__bf16)f1.x; av[5] = (__bf16)f1.y; av[6] = (__bf16)f1.z; av[7] = (__bf16)f1.w;
      if (valid) *(bf16x8*)(xbout + (size_t)arow * 128 + koff + kt * 32) = av;
    } else {
      const bf16x8* gA = (const bf16x8*)((const __bf16*)xin + (size_t)arow * 128 + koff);
      av = valid ? gA[kt * 4] : (bf16x8)(__bf16)0.0f;
    }
    acc = __builtin_amdgcn_mfma_f32_16x16x32_bf16(av, bv, acc, 0, 0, 0);
  }
  #pragma unroll
  for (int j = 0; j < 4; ++j) {
    int row = nb + (l >> 4) * 4 + j;
    if (row < N) qkv[(size_t)row * 16 + (l & 15)] = acc[j];
  }
}

// ------------------- softmax + gather aggregate (to agg) ---------------------
// One wave per node; LDS row accumulator [1024] f32 per wave.
// 4-edge batches: 16 lanes x bf16x8 per edge (one dwordx4 insn = 4 rows);
// ds_bpermute broadcasts record+weight; accumulate via 4 exec-mask-
// serialized group steps (plain float4 LDS RMW, same-wave ordering).

__global__ __launch_bounds__(256) void k_agg2(const int* __restrict__ row_ptr, const int* __restrict__ recs,
                                              const float* __restrict__ qkv, const __bf16* __restrict__ xb,
                                              __bf16* __restrict__ agg, int N) {
  __shared__ float lacc[4][1024];
  int wv = threadIdx.x >> 6;
  int lane = threadIdx.x & 63;
  int n = blockIdx.x * 4 + wv;
  if (n >= N) return;
  float* A = lacc[wv];
  float4* A4 = (float4*)A;
  #pragma unroll
  for (int i = 0; i < 4; ++i) A4[lane + i * 64] = make_float4(0.f, 0.f, 0.f, 0.f);

  int start = row_ptr[n], end = row_ptr[n + 1];
  const float* qvn = qkv + (size_t)n * 16;
  float denom = 0.f, m_run = -1e30f;
  int sub = lane & 15;
  int grp = lane >> 4;
  int permbase = grp * 4;                // bpermute byte index base

  for (int c0 = start; c0 < end; c0 += 64) {
    int cend = (end < c0 + 64) ? end : (c0 + 64);
    int cnt = cend - c0;
    int p = c0 + lane;
    float a = -1e30f; int rec = 0;
    if (p < cend) {
      rec = recs[p];
      int s = rec & 0x1FFFF, r = (rec >> 17) & 7;
      float t = qvn[r] + qkv[(size_t)s * 16 + 8 + r];
      a = (t >= 0.f) ? t : 0.2f * t;
    }
    float cm = a;
    #pragma unroll
    for (int off = 32; off; off >>= 1) cm = fmaxf(cm, __shfl_xor(cm, off, 64));
    if (cm > m_run) {
      if (m_run > -1e29f) {
        float scale = __expf(m_run - cm);
        denom *= scale;
        #pragma unroll
        for (int i = 0; i < 4; ++i) {
          float4 c = A4[lane + i * 64];
          c.x *= scale; c.y *= scale; c.z *= scale; c.w *= scale;
          A4[lane + i * 64] = c;
        }
      }
      m_run = cm;
    }
    float wgt = (p < cend) ? __expf(a - m_run) : 0.f;  // 0 for pad lanes -> harmless
    float ws = wgt;
    #pragma unroll
    for (int off = 32; off; off >>= 1) ws += __shfl_xor(ws, off, 64);
    denom += ws;
    int wbits = __float_as_int(wgt);

    int nbatch = (cnt + 3) >> 2;
    #pragma unroll 2
    for (int b = 0; b < nbatch; ++b) {
      int idx = permbase + b * 16;                          // -> lane b*4+grp
      int rg = __builtin_amdgcn_ds_bpermute(idx, rec);
      int wg = __builtin_amdgcn_ds_bpermute(idx, wbits);
      float fw = __int_as_float(wg);
      int s_ = rg & 0x1FFFF;
      int r_ = (rg >> 17) & 7;
      bf16x8 xv = *(const bf16x8*)(xb + (size_t)s_ * 128 + sub * 8);
      float* ap = &A[r_ * 128 + sub * 8];
      float c0v[8];
      #pragma unroll
      for (int j = 0; j < 8; ++j) c0v[j] = fw * (float)xv[j];
      // 4 serialized group steps: same-wave LDS ops are ordered -> collision-safe
      #pragma unroll
      for (int g = 0; g < 4; ++g) {
        if (grp == g) {
          float4 a0 = *(float4*)ap;
          float4 a1 = *(float4*)(ap + 4);
          a0.x += c0v[0]; a0.y += c0v[1]; a0.z += c0v[2]; a0.w += c0v[3];
          a1.x += c0v[4]; a1.y += c0v[5]; a1.z += c0v[6]; a1.w += c0v[7];
          *(float4*)ap = a0;
          *(float4*)(ap + 4) = a1;
        }
      }
    }
  }

  float inv = 1.f / (denom + 1e-16f);
  __bf16* ag = agg + (size_t)n * 1024;
  #pragma unroll
  for (int i = 0; i < 4; ++i) {
    float4 c = A4[lane + i * 64];
    bf16x4 o;
    o.x = (__bf16)(c.x * inv); o.y = (__bf16)(c.y * inv);
    o.z = (__bf16)(c.z * inv); o.w = (__bf16)(c.w * inv);
    *(bf16x4*)(ag + (size_t)(lane + i * 64) * 4) = o;
  }
}

// --------------------------- MFMA GEMM (K=1024) ------------------------------

#define LSTR 72

__global__ __launch_bounds__(256) void k_gemm(const __bf16* __restrict__ A, const __bf16* __restrict__ B,
                                              const float* __restrict__ bias, __bf16* __restrict__ C, int M) {
  __shared__ __bf16 As[128 * LSTR];
  __shared__ __bf16 Bs[128 * LSTR];
  int bm = blockIdx.x * 128;
  int tid = threadIdx.x;
  int w = tid >> 6, l = tid & 63;

  f32x4 acc[2][8];
  #pragma unroll
  for (int m2 = 0; m2 < 2; ++m2)
    #pragma unroll
    for (int n2 = 0; n2 < 8; ++n2) acc[m2][n2] = (f32x4)0.f;

  int srow = tid >> 1;
  int cbase = (tid & 1) * 4;
  bool valid = (bm + srow) < M;
  const bf16x8* gA = (const bf16x8*)(A + (size_t)(bm + srow) * 1024);
  const bf16x8* gB = (const bf16x8*)(B + (size_t)srow * 1024);

  bf16x8 av[4], bv[4];
  #pragma unroll
  for (int i = 0; i < 4; ++i) {
    av[i] = valid ? gA[cbase + i] : (bf16x8)(__bf16)0.0f;
    bv[i] = gB[cbase + i];
  }

  for (int kt = 0; kt < 16; ++kt) {
    if (kt) __syncthreads();
    #pragma unroll
    for (int i = 0; i < 4; ++i) {
      *(bf16x8*)&As[srow * LSTR + (cbase + i) * 8] = av[i];
      *(bf16x8*)&Bs[srow * LSTR + (cbase + i) * 8] = bv[i];
    }
    __syncthreads();
    if (kt < 15) {
      #pragma unroll
      for (int i = 0; i < 4; ++i) {
        av[i] = valid ? gA[(kt + 1) * 8 + cbase + i] : (bf16x8)(__bf16)0.0f;
        bv[i] = gB[(kt + 1) * 8 + cbase + i];
      }
    }
    #pragma unroll
    for (int ks = 0; ks < 2; ++ks) {
      bf16x8 af[2], bfv[8];
      #pragma unroll
      for (int m2 = 0; m2 < 2; ++m2)
        af[m2] = *(const bf16x8*)&As[(w * 32 + m2 * 16 + (l & 15)) * LSTR + ks * 32 + (l >> 4) * 8];
      #pragma unroll
      for (int n2 = 0; n2 < 8; ++n2)
        bfv[n2] = *(const bf16x8*)&Bs[(n2 * 16 + (l & 15)) * LSTR + ks * 32 + (l >> 4) * 8];
      #pragma unroll
      for (int m2 = 0; m2 < 2; ++m2)
        #pragma unroll
        for (int n2 = 0; n2 < 8; ++n2)
          acc[m2][n2] = __builtin_amdgcn_mfma_f32_16x16x32_bf16(af[m2], bfv[n2], acc[m2][n2], 0, 0, 0);
    }
  }

  #pragma unroll
  for (int m2 = 0; m2 < 2; ++m2)
    #pragma unroll
    for (int j = 0; j < 4; ++j) {
      int row = w * 32 + m2 * 16 + (l >> 4) * 4 + j;
      if (bm + row < M) {
        #pragma unroll
        for (int n2 = 0; n2 < 8; ++n2) {
          float v = acc[m2][n2][j] + bias[n2 * 16 + (l & 15)];
          v = v > 0.f ? v : 0.f;
          C[(size_t)(bm + row) * 128 + n2 * 16 + (l & 15)] = (__bf16)v;
        }
      }
    }
}

// ------------------------------- pool + head ---------------------------------

__global__ __launch_bounds__(256) void k_pool(const __bf16* __restrict__ h, float* __restrict__ gsum,
                                              float* __restrict__ gmax, int N) {
  int c2 = threadIdx.x & 63;
  int grp = threadIdx.x >> 6;
  float s0 = 0.f, s1 = 0.f, m0 = 0.f, m1 = 0.f;
  for (int n = blockIdx.x * 4 + grp; n < N; n += gridDim.x * 4) {
    bf16x2 v = ((const bf16x2*)(h + (size_t)n * 128))[c2];
    float v0 = (float)v.x, v1 = (float)v.y;
    s0 += v0; s1 += v1;
    m0 = fmaxf(m0, v0); m1 = fmaxf(m1, v1);
  }
  __shared__ float ss0[256], ss1[256], sm0[256], sm1[256];
  ss0[threadIdx.x] = s0; ss1[threadIdx.x] = s1;
  sm0[threadIdx.x] = m0; sm1[threadIdx.x] = m1;
  __syncthreads();
  if (grp == 0) {
    #pragma unroll
    for (int g = 1; g < 4; ++g) {
      s0 += ss0[g * 64 + c2]; s1 += ss1[g * 64 + c2];
      m0 = fmaxf(m0, sm0[g * 64 + c2]); m1 = fmaxf(m1, sm1[g * 64 + c2]);
    }
    atomicAdd(&gsum[2 * c2 + 0], s0);
    atomicAdd(&gsum[2 * c2 + 1], s1);
    atomicMax((int*)gmax + 2 * c2 + 0, __float_as_int(m0));
    atomicMax((int*)gmax + 2 * c2 + 1, __float_as_int(m1));
  }
}

__global__ void k_head(const float* __restrict__ gsum, const float* __restrict__ gmax,
                       const float* __restrict__ fc1w, const float* __restrict__ fc1b,
                       const float* __restrict__ fc2w, const float* __restrict__ fc2b,
                       float* __restrict__ out, int N) {
  __shared__ float g[256];
  __shared__ float red[128];
  int t = threadIdx.x;
  if (t < 128) g[t] = tanhf(gsum[t] / (float)N);
  else g[t] = tanhf(gmax[t - 128]);
  __syncthreads();
  float r1 = 0.f;
  if (t < 128) {
    float a = fc1b[t];
    for (int i = 0; i < 256; i++) a += g[i] * fc1w[i * 128 + t];
    r1 = a > 0.f ? a : 0.f;
    red[t] = r1 * fc2w[t];
  }
  __syncthreads();
  for (int s = 64; s > 0; s >>= 1) {
    if (t < s) red[t] += red[t + s];
    __syncthreads();
  }
  if (t == 0) {
    float o = red[0] + fc2b[0];
    out[0] = 1.f / (1.f + __expf(-o));
  }
}

// --------------------------------- launch ------------------------------------

extern "C" void kernel_launch(void* const* d_in, const int* in_sizes, int n_in,
                              void* d_out, int out_size, void* d_ws, size_t ws_size,
                              hipStream_t stream) {
  const float* x    = (const float*)d_in[0];
  const int*   ei   = (const int*)d_in[1];
  const int*   ety  = (const int*)d_in[2];
  const float* w0   = (const float*)d_in[3];
  const float* q0   = (const float*)d_in[4];
  const float* k0   = (const float*)d_in[5];
  const float* b0   = (const float*)d_in[6];
  const float* w1   = (const float*)d_in[7];
  const float* q1   = (const float*)d_in[8];
  const float* k1   = (const float*)d_in[9];
  const float* b1   = (const float*)d_in[10];
  const float* fc1w = (const float*)d_in[11];
  const float* fc1b = (const float*)d_in[12];
  const float* fc2w = (const float*)d_in[13];
  const float* fc2b = (const float*)d_in[14];
  int N = in_sizes[0] / 128;
  int E = in_sizes[2];
  const int* src = ei;
  const int* dst = ei + E;

  char* base = (char*)d_ws;
  size_t off = 0;
  auto alloc = [&](size_t bytes) -> void* {
    off = (off + 255) & ~(size_t)255;
    void* p = base + off;
    off += bytes;
    return p;
  };
  int ncb = (N + (1 << CBSH) - 1) >> CBSH;

  int*    row_ptr = (int*)alloc((size_t)(N + 1) * 4);
  int*    chist   = (int*)alloc(64 * 4);
  int*    cbase   = (int*)alloc(65 * 4);
  int*    ccur    = (int*)alloc(64 * 4);
  int*    tmp     = (int*)alloc((size_t)E * 4);
  int*    recs    = (int*)alloc((size_t)E * 4);
  float*  qkv     = (float*)alloc((size_t)N * 16 * 4);
  float*  gsum    = (float*)alloc(128 * 4);
  float*  gmax    = (float*)alloc(128 * 4);
  __bf16* wqkb    = (__bf16*)alloc(2048 * 2);
  __bf16* xb      = (__bf16*)alloc((size_t)N * 128 * 2);
  __bf16* h1b     = (__bf16*)alloc((size_t)N * 128 * 2);
  __bf16* h2b     = (__bf16*)alloc((size_t)N * 128 * 2);
  __bf16* WT2     = (__bf16*)alloc((size_t)128 * 1024 * 2);
  __bf16* agg     = (__bf16*)alloc((size_t)N * 1024 * 2);

  // CSR build
  hipMemsetAsync(chist, 0, 64 * 4, stream);
  k_chist<<<256, 256, 0, stream>>>(dst, chist, E);
  k_cscan<<<1, 64, 0, stream>>>(chist, cbase, ccur, ncb, E);
  k_cscatter<<<(E + CSC_CH - 1) / CSC_CH, 256, 0, stream>>>(src, dst, ety, ccur, tmp, E);
  k_fsort<<<ncb, 1024, 0, stream>>>(cbase, tmp, recs, row_ptr, N, E);

  for (int layer = 0; layer < 2; ++layer) {
    const float*  W    = layer ? w1 : w0;
    const float*  qq   = layer ? q1 : q0;
    const float*  kk   = layer ? k1 : k0;
    const float*  bb   = layer ? b1 : b0;
    const __bf16* xinb = layer ? h1b : xb;
    __bf16*       hout = layer ? h2b : h1b;

    k_wprep<<<384, 256, 0, stream>>>(W, qq, kk, wqkb, WT2);
    if (layer == 0)
      k_qkv<1><<<(N + 63) / 64, 256, 0, stream>>>((const void*)x, wqkb, qkv, xb, N);
    else
      k_qkv<0><<<(N + 63) / 64, 256, 0, stream>>>((const void*)xinb, wqkb, qkv, nullptr, N);
    k_agg2<<<(N + 3) / 4, 256, 0, stream>>>(row_ptr, recs, qkv, xinb, agg, N);
    k_gemm<<<(N + 127) / 128, 256, 0, stream>>>(agg, WT2, bb, hout, N);
  }

  hipMemsetAsync(gsum, 0, 128 * 4, stream);
  hipMemsetAsync(gmax, 0, 128 * 4, stream);
  k_pool<<<256, 256, 0, stream>>>(h2b, gsum, gmax, N);
  k_head<<<1, 256, 0, stream>>>(gsum, gmax, fc1w, fc1b, fc2w, fc2b, (float*)d_out, N);
}

// Round 9
// 286.237 us; speedup vs baseline: 4.7488x; 1.0092x over previous
//
#include <hip/hip_runtime.h>
#include <hip/hip_bf16.h>

// ---------------------------------------------------------------------------
// RGAT: 2x RGATConv (R=8, H=128) + mean/max pool + MLP head -> scalar
//
// R9 structure (transform-first + batched register-accumulator gather):
//   CSR build (2-level bucket sort, block-owned write windows)
//   per layer:
//     k_wprep: wqkb[16][128] = bf16(W@q|W@k)  +  WT2[h][r*128+k] (merged)
//     k_qkv<L0>: qkv[N][16] = xb @ wqkb^T (MFMA); L0 also emits xb=bf16(x)
//     k_gemmY: Y[r][n][h] = xb @ W[r]    (bf16 MFMA, 128x128 tiles)
//     k_aggY:  h[n] = relu(bias + (1/denom) sum_e w_e * Y[et][src])
//              1 wave/node; online-softmax lane-parallel; 4-edge batches
//              (16 lanes x bf16x8/edge, 1 dwordx4 = 4 edges), REGISTER
//              accumulators acc[8]/lane + cross-group shfl reduce. No LDS.
//   pool (mean+max) -> tanh -> fc1 relu -> fc2 -> sigmoid
//
// Record packing: rec = src | et<<17 | dlow<<20   (N < 2^17, dlow = dst&1023)
// ---------------------------------------------------------------------------

typedef __bf16 bf16x8 __attribute__((ext_vector_type(8)));
typedef __bf16 bf16x4 __attribute__((ext_vector_type(4)));
typedef __bf16 bf16x2 __attribute__((ext_vector_type(2)));
typedef float f32x4 __attribute__((ext_vector_type(4)));

#define CBSH 10                 // coarse bucket = 1024 nodes
#define CSC_CH 4096             // edges per cscatter block

// ----------------------------- CSR build -----------------------------------

__global__ __launch_bounds__(256) void k_chist(const int* __restrict__ dst, int* __restrict__ chist, int E) {
  __shared__ int lh[64];
  int t = threadIdx.x;
  if (t < 64) lh[t] = 0;
  __syncthreads();
  for (int e = blockIdx.x * 256 + t; e < E; e += gridDim.x * 256)
    atomicAdd(&lh[dst[e] >> CBSH], 1);
  __syncthreads();
  if (t < 64 && lh[t]) atomicAdd(&chist[t], lh[t]);
}

__global__ void k_cscan(const int* __restrict__ chist, int* __restrict__ cbase, int* __restrict__ ccur,
                        int ncb, int E) {
  if (threadIdx.x == 0) {
    int acc = 0;
    for (int i = 0; i < ncb; ++i) { cbase[i] = acc; ccur[i] = acc; acc += chist[i]; }
    cbase[ncb] = E;
  }
}

__global__ __launch_bounds__(256) void k_cscatter(const int* __restrict__ src, const int* __restrict__ dst,
                                                  const int* __restrict__ et, int* __restrict__ ccur,
                                                  int* __restrict__ tmp, int E) {
  __shared__ int recbuf[CSC_CH];
  __shared__ int lcnt[64], lbase[64], gbase[64], lcur[64];
  int t = threadIdx.x;
  int base = blockIdx.x * CSC_CH;
  int cnt = E - base; if (cnt > CSC_CH) cnt = CSC_CH;
  if (t < 64) lcnt[t] = 0;
  __syncthreads();
  int myrec[CSC_CH / 256], mycb[CSC_CH / 256];
  int k = 0;
  for (int i = t; i < cnt; i += 256, ++k) {
    int d = dst[base + i];
    int cb = d >> CBSH;
    myrec[k] = src[base + i] | (et[base + i] << 17) | ((d & ((1 << CBSH) - 1)) << 20);
    mycb[k] = cb;
    atomicAdd(&lcnt[cb], 1);
  }
  __syncthreads();
  if (t == 0) {
    int acc = 0;
    for (int c = 0; c < 64; ++c) { lbase[c] = acc; lcur[c] = acc; acc += lcnt[c]; }
  }
  __syncthreads();
  if (t < 64 && lcnt[t] > 0) gbase[t] = atomicAdd(&ccur[t], lcnt[t]);
  __syncthreads();
  k = 0;
  for (int i = t; i < cnt; i += 256, ++k) {
    int p = atomicAdd(&lcur[mycb[k]], 1);
    recbuf[p] = myrec[k];
  }
  __syncthreads();
  for (int i = t; i < cnt; i += 256) {
    int lo = 0, hi = 63;
    while (lo < hi) { int mid = (lo + hi + 1) >> 1; if (lbase[mid] <= i) lo = mid; else hi = mid - 1; }
    tmp[gbase[lo] + (i - lbase[lo])] = recbuf[i];
  }
}

__global__ __launch_bounds__(1024) void k_fsort(const int* __restrict__ cbase, const int* __restrict__ tmp,
                                                int* __restrict__ recs, int* __restrict__ row_ptr,
                                                int N, int E) {
  __shared__ int sd[1024];
  __shared__ int ncur[1024];
  int cb = blockIdx.x, t = threadIdx.x;
  int n0 = cb << CBSH;
  int begin = cbase[cb], endd = cbase[cb + 1];
  sd[t] = 0;
  __syncthreads();
  for (int i = begin + t; i < endd; i += 1024)
    atomicAdd(&sd[(tmp[i] >> 20) & 1023], 1);
  __syncthreads();
  int myc = sd[t];
  for (int off = 1; off < 1024; off <<= 1) {
    int xv = 0; if (t >= off) xv = sd[t - off];
    __syncthreads();
    sd[t] += xv;
    __syncthreads();
  }
  int ex = sd[t] - myc;
  int node = n0 + t;
  if (node < N) row_ptr[node] = begin + ex;
  if (node == N - 1) row_ptr[N] = E;
  ncur[t] = begin + ex;
  __syncthreads();
  for (int i = begin + t; i < endd; i += 1024) {
    int rc = tmp[i];
    int p = atomicAdd(&ncur[(rc >> 20) & 1023], 1);
    recs[p] = rc & 0xFFFFF;                        // src | et<<17
  }
}

// ----------------------- merged weight precompute ----------------------------
// blocks 0..255: wqkb rows; blocks 256..383: WT2 transpose tiles.

__global__ __launch_bounds__(256) void k_wprep(const float* __restrict__ W, const float* __restrict__ q,
                                               const float* __restrict__ k, __bf16* __restrict__ wqkb,
                                               __bf16* __restrict__ WT) {
  if (blockIdx.x < 256) {
    int g = blockIdx.x * 4 + (threadIdx.x >> 6);
    int lane = threadIdx.x & 63;
    const float2* wrow = (const float2*)(W + (size_t)g * 128);
    float2 wv = wrow[lane];
    float2 qv2 = ((const float2*)q)[lane];
    float2 kv2 = ((const float2*)k)[lane];
    float aq = wv.x * qv2.x + wv.y * qv2.y;
    float ak = wv.x * kv2.x + wv.y * kv2.y;
    #pragma unroll
    for (int off = 32; off; off >>= 1) {
      aq += __shfl_xor(aq, off, 64);
      ak += __shfl_xor(ak, off, 64);
    }
    if (lane == 0) { wqkb[g] = (__bf16)aq; wqkb[1024 + g] = (__bf16)ak; }
  } else {
    __shared__ float t[32][33];
    int bb = blockIdx.x - 256;
    int r = bb >> 4;
    int rem = bb & 15;
    int k0 = (rem & 3) * 32, h0 = (rem >> 2) * 32;
    int tx = threadIdx.x & 31;
    int ty = threadIdx.x >> 5;
    #pragma unroll
    for (int i = 0; i < 4; ++i) {
      int kk = ty + i * 8;
      t[kk][tx] = W[((size_t)r * 128 + k0 + kk) * 128 + h0 + tx];
    }
    __syncthreads();
    #pragma unroll
    for (int i = 0; i < 4; ++i) {
      int hh = ty + i * 8;
      WT[(size_t)(h0 + hh) * 1024 + r * 128 + k0 + tx] = (__bf16)t[tx][hh];
    }
  }
}

// qkv[n][c] = xin[n]·wqkb[c]; L0 variant reads f32 x and emits xb = bf16(x).
template <int L0>
__global__ __launch_bounds__(256) void k_qkv(const void* __restrict__ xin, const __bf16* __restrict__ wqkb,
                                             float* __restrict__ qkv, __bf16* __restrict__ xbout, int N) {
  int wv = threadIdx.x >> 6, l = threadIdx.x & 63;
  int nb = blockIdx.x * 64 + wv * 16;
  if (nb >= N) return;
  int arow = nb + (l & 15);
  bool valid = arow < N;
  int koff = (l >> 4) * 8;
  const bf16x8* gB = (const bf16x8*)(wqkb + (size_t)(l & 15) * 128 + koff);
  f32x4 acc = (f32x4)0.f;
  #pragma unroll
  for (int kt = 0; kt < 4; ++kt) {
    bf16x8 bv = gB[kt * 4];
    bf16x8 av;
    if (L0) {
      const float* gA = (const float*)xin + (size_t)arow * 128 + koff + kt * 32;
      float4 f0 = make_float4(0.f, 0.f, 0.f, 0.f), f1 = f0;
      if (valid) { f0 = *(const float4*)gA; f1 = *(const float4*)(gA + 4); }
      av[0] = (__bf16)f0.x; av[1] = (__bf16)f0.y; av[2] = (__bf16)f0.z; av[3] = (__bf16)f0.w;
      av[4] = (__bf16)f1.x; av[5] = (__bf16)f1.y; av[6] = (__bf16)f1.z; av[7] = (__bf16)f1.w;
      if (valid) *(bf16x8*)(xbout + (size_t)arow * 128 + koff + kt * 32) = av;
    } else {
      const bf16x8* gA = (const bf16x8*)((const __bf16*)xin + (size_t)arow * 128 + koff);
      av = valid ? gA[kt * 4] : (bf16x8)(__bf16)0.0f;
    }
    acc = __builtin_amdgcn_mfma_f32_16x16x32_bf16(av, bv, acc, 0, 0, 0);
  }
  #pragma unroll
  for (int j = 0; j < 4; ++j) {
    int row = nb + (l >> 4) * 4 + j;
    if (row < N) qkv[(size_t)row * 16 + (l & 15)] = acc[j];
  }
}

// --------------------------- transform GEMM ----------------------------------
// Y[r][m][h] = sum_k A[m][k] * W[r][k][h]; B^T rows from WT2[h][r*128+k].
// Block 128x128, 4 waves, BK=64, 2 K-iters, LDS stride 72.

#define LSTR 72

__global__ __launch_bounds__(256) void k_gemmY(const __bf16* __restrict__ A,
                                               const __bf16* __restrict__ WT2,
                                               __bf16* __restrict__ Y, int M) {
  __shared__ __bf16 As[128 * LSTR];
  __shared__ __bf16 Bs[128 * LSTR];
  int r = blockIdx.y;
  int bm = blockIdx.x * 128;
  int tid = threadIdx.x;
  int w = tid >> 6, l = tid & 63;
  const __bf16* Br = WT2 + (size_t)r * 128;      // row h at Br + h*1024

  f32x4 acc[2][8];
  #pragma unroll
  for (int m2 = 0; m2 < 2; ++m2)
    #pragma unroll
    for (int n2 = 0; n2 < 8; ++n2) acc[m2][n2] = (f32x4)0.f;

  int srow = tid >> 1;            // staging row 0..127
  int cbase = (tid & 1) * 4;      // 16B-chunk base within 64-elem segment
  bool valid = (bm + srow) < M;

  for (int kt = 0; kt < 2; ++kt) {
    if (kt) __syncthreads();
    bf16x8 av[4], bv[4];
    const bf16x8* gA = (const bf16x8*)(A + (size_t)(bm + srow) * 128 + kt * 64);
    const bf16x8* gB = (const bf16x8*)(Br + (size_t)srow * 1024 + kt * 64);
    #pragma unroll
    for (int i = 0; i < 4; ++i) {
      av[i] = valid ? gA[cbase + i] : (bf16x8)(__bf16)0.0f;
      bv[i] = gB[cbase + i];
    }
    #pragma unroll
    for (int i = 0; i < 4; ++i) {
      *(bf16x8*)&As[srow * LSTR + (cbase + i) * 8] = av[i];
      *(bf16x8*)&Bs[srow * LSTR + (cbase + i) * 8] = bv[i];
    }
    __syncthreads();
    #pragma unroll
    for (int ks = 0; ks < 2; ++ks) {
      bf16x8 af[2], bfv[8];
      #pragma unroll
      for (int m2 = 0; m2 < 2; ++m2)
        af[m2] = *(const bf16x8*)&As[(w * 32 + m2 * 16 + (l & 15)) * LSTR + ks * 32 + (l >> 4) * 8];
      #pragma unroll
      for (int n2 = 0; n2 < 8; ++n2)
        bfv[n2] = *(const bf16x8*)&Bs[(n2 * 16 + (l & 15)) * LSTR + ks * 32 + (l >> 4) * 8];
      #pragma unroll
      for (int m2 = 0; m2 < 2; ++m2)
        #pragma unroll
        for (int n2 = 0; n2 < 8; ++n2)
          acc[m2][n2] = __builtin_amdgcn_mfma_f32_16x16x32_bf16(af[m2], bfv[n2], acc[m2][n2], 0, 0, 0);
    }
  }

  // C/D layout: col = lane&15, row = (lane>>4)*4 + reg
  __bf16* Yr = Y + ((size_t)r * M + bm) * 128;
  #pragma unroll
  for (int m2 = 0; m2 < 2; ++m2)
    #pragma unroll
    for (int j = 0; j < 4; ++j) {
      int row = w * 32 + m2 * 16 + (l >> 4) * 4 + j;
      if (bm + row < M) {
        #pragma unroll
        for (int n2 = 0; n2 < 8; ++n2)
          Yr[(size_t)row * 128 + n2 * 16 + (l & 15)] = (__bf16)acc[m2][n2][j];
      }
    }
}

// ------------------- softmax + gather aggregate (register acc) ---------------
// One wave per node. 4-edge batches: group g (16 lanes) handles edge g+4b,
// lane sub owns channels sub*8..sub*8+7 (bf16x8 gather). acc[8] f32 per lane
// holds the group's partial; 2 shfl_xor steps reduce groups at the end.

__global__ __launch_bounds__(256) void k_aggY(const int* __restrict__ row_ptr, const int* __restrict__ recs,
                                              const float* __restrict__ qkv, const __bf16* __restrict__ Y,
                                              const float* __restrict__ bias, __bf16* __restrict__ hout,
                                              int N) {
  int wv = threadIdx.x >> 6;
  int lane = threadIdx.x & 63;
  int n = blockIdx.x * 4 + wv;
  if (n >= N) return;
  int start = row_ptr[n], end = row_ptr[n + 1];
  const float* qvn = qkv + (size_t)n * 16;
  float denom = 0.f, m_run = -1e30f;
  int sub = lane & 15;
  int grp = lane >> 4;
  float acc[8];
  #pragma unroll
  for (int j = 0; j < 8; ++j) acc[j] = 0.f;

  for (int c0 = start; c0 < end; c0 += 64) {
    int cend = (end < c0 + 64) ? end : (c0 + 64);
    int cnt = cend - c0;
    int p = c0 + lane;
    float a = -1e30f; int rec = 0;
    if (p < cend) {
      rec = recs[p];
      int s = rec & 0x1FFFF, r = (rec >> 17) & 7;
      float t = qvn[r] + qkv[(size_t)s * 16 + 8 + r];
      a = (t >= 0.f) ? t : 0.2f * t;
    }
    float cm = a;
    #pragma unroll
    for (int off = 32; off; off >>= 1) cm = fmaxf(cm, __shfl_xor(cm, off, 64));
    if (cm > m_run) {
      if (m_run > -1e29f) {
        float scale = __expf(m_run - cm);
        denom *= scale;
        #pragma unroll
        for (int j = 0; j < 8; ++j) acc[j] *= scale;
      }
      m_run = cm;
    }
    float wgt = (p < cend) ? __expf(a - m_run) : 0.f;   // 0 on pad lanes
    float ws = wgt;
    #pragma unroll
    for (int off = 32; off; off >>= 1) ws += __shfl_xor(ws, off, 64);
    denom += ws;
    int wbits = __float_as_int(wgt);

    int nbatch = (cnt + 3) >> 2;
    #pragma unroll 2
    for (int b = 0; b < nbatch; ++b) {
      int idx = grp * 4 + b * 16;                         // -> lane grp+4b
      int rg = __builtin_amdgcn_ds_bpermute(idx, rec);
      int wg = __builtin_amdgcn_ds_bpermute(idx, wbits);
      float fw = __int_as_float(wg);
      int s_ = rg & 0x1FFFF;
      int r_ = (rg >> 17) & 7;
      bf16x8 xv = *(const bf16x8*)(Y + ((size_t)r_ * N + s_) * 128 + sub * 8);
      #pragma unroll
      for (int j = 0; j < 8; ++j) acc[j] += fw * (float)xv[j];
    }
  }

  // reduce the 4 group partials (lanes differing in bits 4,5)
  #pragma unroll
  for (int j = 0; j < 8; ++j) {
    acc[j] += __shfl_xor(acc[j], 16, 64);
    acc[j] += __shfl_xor(acc[j], 32, 64);
  }
  float inv = 1.f / (denom + 1e-16f);
  if (grp == 0) {
    float4 b0 = *(const float4*)(bias + sub * 8);
    float4 b1 = *(const float4*)(bias + sub * 8 + 4);
    float bb[8] = {b0.x, b0.y, b0.z, b0.w, b1.x, b1.y, b1.z, b1.w};
    bf16x8 o;
    #pragma unroll
    for (int j = 0; j < 8; ++j) o[j] = (__bf16)fmaxf(acc[j] * inv + bb[j], 0.f);
    *(bf16x8*)(hout + (size_t)n * 128 + sub * 8) = o;
  }
}

// ------------------------------- pool + head ---------------------------------

__global__ __launch_bounds__(256) void k_pool(const __bf16* __restrict__ h, float* __restrict__ gsum,
                                              float* __restrict__ gmax, int N) {
  int c2 = threadIdx.x & 63;
  int grp = threadIdx.x >> 6;
  float s0 = 0.f, s1 = 0.f, m0 = 0.f, m1 = 0.f;
  for (int n = blockIdx.x * 4 + grp; n < N; n += gridDim.x * 4) {
    bf16x2 v = ((const bf16x2*)(h + (size_t)n * 128))[c2];
    float v0 = (float)v.x, v1 = (float)v.y;
    s0 += v0; s1 += v1;
    m0 = fmaxf(m0, v0); m1 = fmaxf(m1, v1);
  }
  __shared__ float ss0[256], ss1[256], sm0[256], sm1[256];
  ss0[threadIdx.x] = s0; ss1[threadIdx.x] = s1;
  sm0[threadIdx.x] = m0; sm1[threadIdx.x] = m1;
  __syncthreads();
  if (grp == 0) {
    #pragma unroll
    for (int g = 1; g < 4; ++g) {
      s0 += ss0[g * 64 + c2]; s1 += ss1[g * 64 + c2];
      m0 = fmaxf(m0, sm0[g * 64 + c2]); m1 = fmaxf(m1, sm1[g * 64 + c2]);
    }
    atomicAdd(&gsum[2 * c2 + 0], s0);
    atomicAdd(&gsum[2 * c2 + 1], s1);
    atomicMax((int*)gmax + 2 * c2 + 0, __float_as_int(m0));
    atomicMax((int*)gmax + 2 * c2 + 1, __float_as_int(m1));
  }
}

__global__ void k_head(const float* __restrict__ gsum, const float* __restrict__ gmax,
                       const float* __restrict__ fc1w, const float* __restrict__ fc1b,
                       const float* __restrict__ fc2w, const float* __restrict__ fc2b,
                       float* __restrict__ out, int N) {
  __shared__ float g[256];
  __shared__ float red[128];
  int t = threadIdx.x;
  if (t < 128) g[t] = tanhf(gsum[t] / (float)N);
  else g[t] = tanhf(gmax[t - 128]);
  __syncthreads();
  float r1 = 0.f;
  if (t < 128) {
    float a = fc1b[t];
    for (int i = 0; i < 256; i++) a += g[i] * fc1w[i * 128 + t];
    r1 = a > 0.f ? a : 0.f;
    red[t] = r1 * fc2w[t];
  }
  __syncthreads();
  for (int s = 64; s > 0; s >>= 1) {
    if (t < s) red[t] += red[t + s];
    __syncthreads();
  }
  if (t == 0) {
    float o = red[0] + fc2b[0];
    out[0] = 1.f / (1.f + __expf(-o));
  }
}

// --------------------------------- launch ------------------------------------

extern "C" void kernel_launch(void* const* d_in, const int* in_sizes, int n_in,
                              void* d_out, int out_size, void* d_ws, size_t ws_size,
                              hipStream_t stream) {
  const float* x    = (const float*)d_in[0];
  const int*   ei   = (const int*)d_in[1];
  const int*   ety  = (const int*)d_in[2];
  const float* w0   = (const float*)d_in[3];
  const float* q0   = (const float*)d_in[4];
  const float* k0   = (const float*)d_in[5];
  const float* b0   = (const float*)d_in[6];
  const float* w1   = (const float*)d_in[7];
  const float* q1   = (const float*)d_in[8];
  const float* k1   = (const float*)d_in[9];
  const float* b1   = (const float*)d_in[10];
  const float* fc1w = (const float*)d_in[11];
  const float* fc1b = (const float*)d_in[12];
  const float* fc2w = (const float*)d_in[13];
  const float* fc2b = (const float*)d_in[14];
  int N = in_sizes[0] / 128;
  int E = in_sizes[2];
  const int* src = ei;
  const int* dst = ei + E;

  char* base = (char*)d_ws;
  size_t off = 0;
  auto alloc = [&](size_t bytes) -> void* {
    off = (off + 255) & ~(size_t)255;
    void* p = base + off;
    off += bytes;
    return p;
  };
  int ncb = (N + (1 << CBSH) - 1) >> CBSH;

  int*    row_ptr = (int*)alloc((size_t)(N + 1) * 4);
  int*    chist   = (int*)alloc(64 * 4);
  int*    cbase   = (int*)alloc(65 * 4);
  int*    ccur    = (int*)alloc(64 * 4);
  int*    tmp     = (int*)alloc((size_t)E * 4);
  int*    recs    = (int*)alloc((size_t)E * 4);
  float*  qkv     = (float*)alloc((size_t)N * 16 * 4);
  float*  gsum    = (float*)alloc(128 * 4);
  float*  gmax    = (float*)alloc(128 * 4);
  __bf16* wqkb    = (__bf16*)alloc(2048 * 2);
  __bf16* xb      = (__bf16*)alloc((size_t)N * 128 * 2);
  __bf16* h1b     = (__bf16*)alloc((size_t)N * 128 * 2);
  __bf16* h2b     = (__bf16*)alloc((size_t)N * 128 * 2);
  __bf16* WT2     = (__bf16*)alloc((size_t)128 * 1024 * 2);
  __bf16* Y       = (__bf16*)alloc((size_t)8 * N * 128 * 2);

  // CSR build
  hipMemsetAsync(chist, 0, 64 * 4, stream);
  k_chist<<<256, 256, 0, stream>>>(dst, chist, E);
  k_cscan<<<1, 64, 0, stream>>>(chist, cbase, ccur, ncb, E);
  k_cscatter<<<(E + CSC_CH - 1) / CSC_CH, 256, 0, stream>>>(src, dst, ety, ccur, tmp, E);
  k_fsort<<<ncb, 1024, 0, stream>>>(cbase, tmp, recs, row_ptr, N, E);

  for (int layer = 0; layer < 2; ++layer) {
    const float*  W    = layer ? w1 : w0;
    const float*  qq   = layer ? q1 : q0;
    const float*  kk   = layer ? k1 : k0;
    const float*  bb   = layer ? b1 : b0;
    const __bf16* xinb = layer ? h1b : xb;
    __bf16*       hout = layer ? h2b : h1b;

    k_wprep<<<384, 256, 0, stream>>>(W, qq, kk, wqkb, WT2);
    if (layer == 0)
      k_qkv<1><<<(N + 63) / 64, 256, 0, stream>>>((const void*)x, wqkb, qkv, xb, N);
    else
      k_qkv<0><<<(N + 63) / 64, 256, 0, stream>>>((const void*)xinb, wqkb, qkv, nullptr, N);
    {
      dim3 g((N + 127) / 128, 8);
      k_gemmY<<<g, 256, 0, stream>>>(xinb, WT2, Y, N);
    }
    k_aggY<<<(N + 3) / 4, 256, 0, stream>>>(row_ptr, recs, qkv, Y, bb, hout, N);
  }

  hipMemsetAsync(gsum, 0, 128 * 4, stream);
  hipMemsetAsync(gmax, 0, 128 * 4, stream);
  k_pool<<<256, 256, 0, stream>>>(h2b, gsum, gmax, N);
  k_head<<<1, 256, 0, stream>>>(gsum, gmax, fc1w, fc1b, fc2w, fc2b, (float*)d_out, N);
}

// Round 10
// 275.926 us; speedup vs baseline: 4.9263x; 1.0374x over previous
//
#include <hip/hip_runtime.h>
#include <hip/hip_bf16.h>

// ---------------------------------------------------------------------------
// RGAT: 2x RGATConv (R=8, H=128) + mean/max pool + MLP head -> scalar
//
// R10 structure (transform-first; A-resident gemmY + 4-deep gather pipeline):
//   CSR build (2-level bucket sort, block-owned write windows)
//   per layer:
//     k_wprep: wqkb[16][128] = bf16(W@q|W@k)  +  WT2[h][r*128+k] (merged)
//     k_qkv<L0>: qkv[N][16] = xb @ wqkb^T (MFMA); L0 also emits xb=bf16(x)
//     k_gemmY: Y[r][n][h] = xb @ W[r]; ONE block per 128-row tile, A staged
//              once in LDS, loop over r staging W[r] (L2-hot) each pass.
//     k_aggY:  h[n] = relu(bias + (1/denom) sum_e w_e * Y[et][src])
//              1 wave/node; online-softmax lane-parallel; 4-edge batches
//              (16 lanes x bf16x8/edge) with 4 batches in flight (MLP=4);
//              register accumulators + cross-group shfl reduce. No LDS.
//   pool (mean+max) -> tanh -> fc1 relu -> fc2 -> sigmoid
//
// Record packing: rec = src | et<<17 | dlow<<20   (N < 2^17, dlow = dst&1023)
// ---------------------------------------------------------------------------

typedef __bf16 bf16x8 __attribute__((ext_vector_type(8)));
typedef __bf16 bf16x4 __attribute__((ext_vector_type(4)));
typedef __bf16 bf16x2 __attribute__((ext_vector_type(2)));
typedef float f32x4 __attribute__((ext_vector_type(4)));

#define CBSH 10                 // coarse bucket = 1024 nodes
#define CSC_CH 4096             // edges per cscatter block

// ----------------------------- CSR build -----------------------------------

__global__ __launch_bounds__(256) void k_chist(const int* __restrict__ dst, int* __restrict__ chist, int E) {
  __shared__ int lh[64];
  int t = threadIdx.x;
  if (t < 64) lh[t] = 0;
  __syncthreads();
  for (int e = blockIdx.x * 256 + t; e < E; e += gridDim.x * 256)
    atomicAdd(&lh[dst[e] >> CBSH], 1);
  __syncthreads();
  if (t < 64 && lh[t]) atomicAdd(&chist[t], lh[t]);
}

__global__ void k_cscan(const int* __restrict__ chist, int* __restrict__ cbase, int* __restrict__ ccur,
                        int ncb, int E) {
  if (threadIdx.x == 0) {
    int acc = 0;
    for (int i = 0; i < ncb; ++i) { cbase[i] = acc; ccur[i] = acc; acc += chist[i]; }
    cbase[ncb] = E;
  }
}

__global__ __launch_bounds__(256) void k_cscatter(const int* __restrict__ src, const int* __restrict__ dst,
                                                  const int* __restrict__ et, int* __restrict__ ccur,
                                                  int* __restrict__ tmp, int E) {
  __shared__ int recbuf[CSC_CH];
  __shared__ int lcnt[64], lbase[64], gbase[64], lcur[64];
  int t = threadIdx.x;
  int base = blockIdx.x * CSC_CH;
  int cnt = E - base; if (cnt > CSC_CH) cnt = CSC_CH;
  if (t < 64) lcnt[t] = 0;
  __syncthreads();
  int myrec[CSC_CH / 256], mycb[CSC_CH / 256];
  int k = 0;
  for (int i = t; i < cnt; i += 256, ++k) {
    int d = dst[base + i];
    int cb = d >> CBSH;
    myrec[k] = src[base + i] | (et[base + i] << 17) | ((d & ((1 << CBSH) - 1)) << 20);
    mycb[k] = cb;
    atomicAdd(&lcnt[cb], 1);
  }
  __syncthreads();
  if (t == 0) {
    int acc = 0;
    for (int c = 0; c < 64; ++c) { lbase[c] = acc; lcur[c] = acc; acc += lcnt[c]; }
  }
  __syncthreads();
  if (t < 64 && lcnt[t] > 0) gbase[t] = atomicAdd(&ccur[t], lcnt[t]);
  __syncthreads();
  k = 0;
  for (int i = t; i < cnt; i += 256, ++k) {
    int p = atomicAdd(&lcur[mycb[k]], 1);
    recbuf[p] = myrec[k];
  }
  __syncthreads();
  for (int i = t; i < cnt; i += 256) {
    int lo = 0, hi = 63;
    while (lo < hi) { int mid = (lo + hi + 1) >> 1; if (lbase[mid] <= i) lo = mid; else hi = mid - 1; }
    tmp[gbase[lo] + (i - lbase[lo])] = recbuf[i];
  }
}

__global__ __launch_bounds__(1024) void k_fsort(const int* __restrict__ cbase, const int* __restrict__ tmp,
                                                int* __restrict__ recs, int* __restrict__ row_ptr,
                                                int N, int E) {
  __shared__ int sd[1024];
  __shared__ int ncur[1024];
  int cb = blockIdx.x, t = threadIdx.x;
  int n0 = cb << CBSH;
  int begin = cbase[cb], endd = cbase[cb + 1];
  sd[t] = 0;
  __syncthreads();
  for (int i = begin + t; i < endd; i += 1024)
    atomicAdd(&sd[(tmp[i] >> 20) & 1023], 1);
  __syncthreads();
  int myc = sd[t];
  for (int off = 1; off < 1024; off <<= 1) {
    int xv = 0; if (t >= off) xv = sd[t - off];
    __syncthreads();
    sd[t] += xv;
    __syncthreads();
  }
  int ex = sd[t] - myc;
  int node = n0 + t;
  if (node < N) row_ptr[node] = begin + ex;
  if (node == N - 1) row_ptr[N] = E;
  ncur[t] = begin + ex;
  __syncthreads();
  for (int i = begin + t; i < endd; i += 1024) {
    int rc = tmp[i];
    int p = atomicAdd(&ncur[(rc >> 20) & 1023], 1);
    recs[p] = rc & 0xFFFFF;                        // src | et<<17
  }
}

// ----------------------- merged weight precompute ----------------------------
// blocks 0..255: wqkb rows; blocks 256..383: WT2 transpose tiles.

__global__ __launch_bounds__(256) void k_wprep(const float* __restrict__ W, const float* __restrict__ q,
                                               const float* __restrict__ k, __bf16* __restrict__ wqkb,
                                               __bf16* __restrict__ WT) {
  if (blockIdx.x < 256) {
    int g = blockIdx.x * 4 + (threadIdx.x >> 6);
    int lane = threadIdx.x & 63;
    const float2* wrow = (const float2*)(W + (size_t)g * 128);
    float2 wv = wrow[lane];
    float2 qv2 = ((const float2*)q)[lane];
    float2 kv2 = ((const float2*)k)[lane];
    float aq = wv.x * qv2.x + wv.y * qv2.y;
    float ak = wv.x * kv2.x + wv.y * kv2.y;
    #pragma unroll
    for (int off = 32; off; off >>= 1) {
      aq += __shfl_xor(aq, off, 64);
      ak += __shfl_xor(ak, off, 64);
    }
    if (lane == 0) { wqkb[g] = (__bf16)aq; wqkb[1024 + g] = (__bf16)ak; }
  } else {
    __shared__ float t[32][33];
    int bb = blockIdx.x - 256;
    int r = bb >> 4;
    int rem = bb & 15;
    int k0 = (rem & 3) * 32, h0 = (rem >> 2) * 32;
    int tx = threadIdx.x & 31;
    int ty = threadIdx.x >> 5;
    #pragma unroll
    for (int i = 0; i < 4; ++i) {
      int kk = ty + i * 8;
      t[kk][tx] = W[((size_t)r * 128 + k0 + kk) * 128 + h0 + tx];
    }
    __syncthreads();
    #pragma unroll
    for (int i = 0; i < 4; ++i) {
      int hh = ty + i * 8;
      WT[(size_t)(h0 + hh) * 1024 + r * 128 + k0 + tx] = (__bf16)t[tx][hh];
    }
  }
}

// qkv[n][c] = xin[n]·wqkb[c]; L0 variant reads f32 x and emits xb = bf16(x).
template <int L0>
__global__ __launch_bounds__(256) void k_qkv(const void* __restrict__ xin, const __bf16* __restrict__ wqkb,
                                             float* __restrict__ qkv, __bf16* __restrict__ xbout, int N) {
  int wv = threadIdx.x >> 6, l = threadIdx.x & 63;
  int nb = blockIdx.x * 64 + wv * 16;
  if (nb >= N) return;
  int arow = nb + (l & 15);
  bool valid = arow < N;
  int koff = (l >> 4) * 8;
  const bf16x8* gB = (const bf16x8*)(wqkb + (size_t)(l & 15) * 128 + koff);
  f32x4 acc = (f32x4)0.f;
  #pragma unroll
  for (int kt = 0; kt < 4; ++kt) {
    bf16x8 bv = gB[kt * 4];
    bf16x8 av;
    if (L0) {
      const float* gA = (const float*)xin + (size_t)arow * 128 + koff + kt * 32;
      float4 f0 = make_float4(0.f, 0.f, 0.f, 0.f), f1 = f0;
      if (valid) { f0 = *(const float4*)gA; f1 = *(const float4*)(gA + 4); }
      av[0] = (__bf16)f0.x; av[1] = (__bf16)f0.y; av[2] = (__bf16)f0.z; av[3] = (__bf16)f0.w;
      av[4] = (__bf16)f1.x; av[5] = (__bf16)f1.y; av[6] = (__bf16)f1.z; av[7] = (__bf16)f1.w;
      if (valid) *(bf16x8*)(xbout + (size_t)arow * 128 + koff + kt * 32) = av;
    } else {
      const bf16x8* gA = (const bf16x8*)((const __bf16*)xin + (size_t)arow * 128 + koff);
      av = valid ? gA[kt * 4] : (bf16x8)(__bf16)0.0f;
    }
    acc = __builtin_amdgcn_mfma_f32_16x16x32_bf16(av, bv, acc, 0, 0, 0);
  }
  #pragma unroll
  for (int j = 0; j < 4; ++j) {
    int row = nb + (l >> 4) * 4 + j;
    if (row < N) qkv[(size_t)row * 16 + (l & 15)] = acc[j];
  }
}

// --------------------------- transform GEMM ----------------------------------
// Y[r][m][h] = sum_k A[m][k] * W[r][k][h]; B^T rows from WT2[h][r*128+k].
// ONE block per 128-row tile: A staged once (full K=128), loop r staging
// W[r] from L2. Stride 136 elems: row shift 4 banks -> 2-way (free).

#define ASTR 136

__global__ __launch_bounds__(256) void k_gemmY(const __bf16* __restrict__ A,
                                               const __bf16* __restrict__ WT2,
                                               __bf16* __restrict__ Y, int M) {
  __shared__ __bf16 As[128 * ASTR];
  __shared__ __bf16 Bs[128 * ASTR];
  int bm = blockIdx.x * 128;
  int tid = threadIdx.x;
  int w = tid >> 6, l = tid & 63;
  int srow = tid >> 1;            // 2 threads per row
  int cb8 = (tid & 1) * 8;        // 8 chunks of 8 elems per thread
  bool valid = (bm + srow) < M;

  // stage A full row (128 elems)
  {
    const bf16x8* gA = (const bf16x8*)(A + (size_t)(bm + srow) * 128);
    #pragma unroll
    for (int i = 0; i < 8; ++i) {
      bf16x8 v = valid ? gA[cb8 + i] : (bf16x8)(__bf16)0.0f;
      *(bf16x8*)&As[srow * ASTR + (cb8 + i) * 8] = v;
    }
  }

  for (int r = 0; r < 8; ++r) {
    __syncthreads();               // Bs free (prev compute done) / As visible
    {
      const bf16x8* gB = (const bf16x8*)(WT2 + (size_t)srow * 1024 + r * 128);
      #pragma unroll
      for (int i = 0; i < 8; ++i)
        *(bf16x8*)&Bs[srow * ASTR + (cb8 + i) * 8] = gB[cb8 + i];
    }
    __syncthreads();

    f32x4 acc[2][8];
    #pragma unroll
    for (int m2 = 0; m2 < 2; ++m2)
      #pragma unroll
      for (int n2 = 0; n2 < 8; ++n2) acc[m2][n2] = (f32x4)0.f;

    #pragma unroll
    for (int ks = 0; ks < 4; ++ks) {
      bf16x8 af[2], bfv[8];
      #pragma unroll
      for (int m2 = 0; m2 < 2; ++m2)
        af[m2] = *(const bf16x8*)&As[(w * 32 + m2 * 16 + (l & 15)) * ASTR + ks * 32 + (l >> 4) * 8];
      #pragma unroll
      for (int n2 = 0; n2 < 8; ++n2)
        bfv[n2] = *(const bf16x8*)&Bs[(n2 * 16 + (l & 15)) * ASTR + ks * 32 + (l >> 4) * 8];
      #pragma unroll
      for (int m2 = 0; m2 < 2; ++m2)
        #pragma unroll
        for (int n2 = 0; n2 < 8; ++n2)
          acc[m2][n2] = __builtin_amdgcn_mfma_f32_16x16x32_bf16(af[m2], bfv[n2], acc[m2][n2], 0, 0, 0);
    }

    // C/D layout: col = lane&15, row = (lane>>4)*4 + reg
    __bf16* Yr = Y + ((size_t)r * M + bm) * 128;
    #pragma unroll
    for (int m2 = 0; m2 < 2; ++m2)
      #pragma unroll
      for (int j = 0; j < 4; ++j) {
        int row = w * 32 + m2 * 16 + (l >> 4) * 4 + j;
        if (bm + row < M) {
          #pragma unroll
          for (int n2 = 0; n2 < 8; ++n2)
            Yr[(size_t)row * 128 + n2 * 16 + (l & 15)] = (__bf16)acc[m2][n2][j];
        }
      }
  }
}

// ------------------- softmax + gather aggregate (register acc) ---------------
// One wave per node. 4-edge batches: group g (16 lanes) handles edge g+4b,
// lane sub owns channels sub*8..sub*8+7. 4 batches kept in flight (MLP=4).

__global__ __launch_bounds__(256) void k_aggY(const int* __restrict__ row_ptr, const int* __restrict__ recs,
                                              const float* __restrict__ qkv, const __bf16* __restrict__ Y,
                                              const float* __restrict__ bias, __bf16* __restrict__ hout,
                                              int N) {
  int wv = threadIdx.x >> 6;
  int lane = threadIdx.x & 63;
  int n = blockIdx.x * 4 + wv;
  if (n >= N) return;
  int start = row_ptr[n], end = row_ptr[n + 1];
  const float* qvn = qkv + (size_t)n * 16;
  float denom = 0.f, m_run = -1e30f;
  int sub = lane & 15;
  int grp = lane >> 4;
  float acc[8];
  #pragma unroll
  for (int j = 0; j < 8; ++j) acc[j] = 0.f;

  for (int c0 = start; c0 < end; c0 += 64) {
    int cend = (end < c0 + 64) ? end : (c0 + 64);
    int cnt = cend - c0;
    int p = c0 + lane;
    float a = -1e30f; int rec = 0;
    if (p < cend) {
      rec = recs[p];
      int s = rec & 0x1FFFF, r = (rec >> 17) & 7;
      float t = qvn[r] + qkv[(size_t)s * 16 + 8 + r];
      a = (t >= 0.f) ? t : 0.2f * t;
    }
    float cm = a;
    #pragma unroll
    for (int off = 32; off; off >>= 1) cm = fmaxf(cm, __shfl_xor(cm, off, 64));
    if (cm > m_run) {
      if (m_run > -1e29f) {
        float scale = __expf(m_run - cm);
        denom *= scale;
        #pragma unroll
        for (int j = 0; j < 8; ++j) acc[j] *= scale;
      }
      m_run = cm;
    }
    float wgt = (p < cend) ? __expf(a - m_run) : 0.f;   // 0 on pad lanes
    float ws = wgt;
    #pragma unroll
    for (int off = 32; off; off >>= 1) ws += __shfl_xor(ws, off, 64);
    denom += ws;
    int wbits = __float_as_int(wgt);

    int nbatch = (cnt + 3) >> 2;
    int b = 0;
    for (; b + 4 <= nbatch; b += 4) {
      int rg[4], wg[4];
      #pragma unroll
      for (int j = 0; j < 4; ++j) {
        int idx = grp * 4 + (b + j) * 16;
        rg[j] = __builtin_amdgcn_ds_bpermute(idx, rec);
        wg[j] = __builtin_amdgcn_ds_bpermute(idx, wbits);
      }
      bf16x8 xv[4];
      #pragma unroll
      for (int j = 0; j < 4; ++j) {
        int s_ = rg[j] & 0x1FFFF;
        int r_ = (rg[j] >> 17) & 7;
        xv[j] = *(const bf16x8*)(Y + ((size_t)r_ * N + s_) * 128 + sub * 8);
      }
      #pragma unroll
      for (int j = 0; j < 4; ++j) {
        float fw = __int_as_float(wg[j]);
        #pragma unroll
        for (int jj = 0; jj < 8; ++jj) acc[jj] += fw * (float)xv[j][jj];
      }
    }
    for (; b < nbatch; ++b) {
      int idx = grp * 4 + b * 16;
      int rg = __builtin_amdgcn_ds_bpermute(idx, rec);
      int wg = __builtin_amdgcn_ds_bpermute(idx, wbits);
      float fw = __int_as_float(wg);
      int s_ = rg & 0x1FFFF;
      int r_ = (rg >> 17) & 7;
      bf16x8 xv = *(const bf16x8*)(Y + ((size_t)r_ * N + s_) * 128 + sub * 8);
      #pragma unroll
      for (int jj = 0; jj < 8; ++jj) acc[jj] += fw * (float)xv[jj];
    }
  }

  // reduce the 4 group partials (lanes differing in bits 4,5)
  #pragma unroll
  for (int j = 0; j < 8; ++j) {
    acc[j] += __shfl_xor(acc[j], 16, 64);
    acc[j] += __shfl_xor(acc[j], 32, 64);
  }
  float inv = 1.f / (denom + 1e-16f);
  if (grp == 0) {
    float4 b0 = *(const float4*)(bias + sub * 8);
    float4 b1 = *(const float4*)(bias + sub * 8 + 4);
    float bb[8] = {b0.x, b0.y, b0.z, b0.w, b1.x, b1.y, b1.z, b1.w};
    bf16x8 o;
    #pragma unroll
    for (int j = 0; j < 8; ++j) o[j] = (__bf16)fmaxf(acc[j] * inv + bb[j], 0.f);
    *(bf16x8*)(hout + (size_t)n * 128 + sub * 8) = o;
  }
}

// ------------------------------- pool + head ---------------------------------

__global__ __launch_bounds__(256) void k_pool(const __bf16* __restrict__ h, float* __restrict__ gsum,
                                              float* __restrict__ gmax, int N) {
  int c2 = threadIdx.x & 63;
  int grp = threadIdx.x >> 6;
  float s0 = 0.f, s1 = 0.f, m0 = 0.f, m1 = 0.f;
  for (int n = blockIdx.x * 4 + grp; n < N; n += gridDim.x * 4) {
    bf16x2 v = ((const bf16x2*)(h + (size_t)n * 128))[c2];
    float v0 = (float)v.x, v1 = (float)v.y;
    s0 += v0; s1 += v1;
    m0 = fmaxf(m0, v0); m1 = fmaxf(m1, v1);
  }
  __shared__ float ss0[256], ss1[256], sm0[256], sm1[256];
  ss0[threadIdx.x] = s0; ss1[threadIdx.x] = s1;
  sm0[threadIdx.x] = m0; sm1[threadIdx.x] = m1;
  __syncthreads();
  if (grp == 0) {
    #pragma unroll
    for (int g = 1; g < 4; ++g) {
      s0 += ss0[g * 64 + c2]; s1 += ss1[g * 64 + c2];
      m0 = fmaxf(m0, sm0[g * 64 + c2]); m1 = fmaxf(m1, sm1[g * 64 + c2]);
    }
    atomicAdd(&gsum[2 * c2 + 0], s0);
    atomicAdd(&gsum[2 * c2 + 1], s1);
    atomicMax((int*)gmax + 2 * c2 + 0, __float_as_int(m0));
    atomicMax((int*)gmax + 2 * c2 + 1, __float_as_int(m1));
  }
}

__global__ void k_head(const float* __restrict__ gsum, const float* __restrict__ gmax,
                       const float* __restrict__ fc1w, const float* __restrict__ fc1b,
                       const float* __restrict__ fc2w, const float* __restrict__ fc2b,
                       float* __restrict__ out, int N) {
  __shared__ float g[256];
  __shared__ float red[128];
  int t = threadIdx.x;
  if (t < 128) g[t] = tanhf(gsum[t] / (float)N);
  else g[t] = tanhf(gmax[t - 128]);
  __syncthreads();
  float r1 = 0.f;
  if (t < 128) {
    float a = fc1b[t];
    for (int i = 0; i < 256; i++) a += g[i] * fc1w[i * 128 + t];
    r1 = a > 0.f ? a : 0.f;
    red[t] = r1 * fc2w[t];
  }
  __syncthreads();
  for (int s = 64; s > 0; s >>= 1) {
    if (t < s) red[t] += red[t + s];
    __syncthreads();
  }
  if (t == 0) {
    float o = red[0] + fc2b[0];
    out[0] = 1.f / (1.f + __expf(-o));
  }
}

// --------------------------------- launch ------------------------------------

extern "C" void kernel_launch(void* const* d_in, const int* in_sizes, int n_in,
                              void* d_out, int out_size, void* d_ws, size_t ws_size,
                              hipStream_t stream) {
  const float* x    = (const float*)d_in[0];
  const int*   ei   = (const int*)d_in[1];
  const int*   ety  = (const int*)d_in[2];
  const float* w0   = (const float*)d_in[3];
  const float* q0   = (const float*)d_in[4];
  const float* k0   = (const float*)d_in[5];
  const float* b0   = (const float*)d_in[6];
  const float* w1   = (const float*)d_in[7];
  const float* q1   = (const float*)d_in[8];
  const float* k1   = (const float*)d_in[9];
  const float* b1   = (const float*)d_in[10];
  const float* fc1w = (const float*)d_in[11];
  const float* fc1b = (const float*)d_in[12];
  const float* fc2w = (const float*)d_in[13];
  const float* fc2b = (const float*)d_in[14];
  int N = in_sizes[0] / 128;
  int E = in_sizes[2];
  const int* src = ei;
  const int* dst = ei + E;

  char* base = (char*)d_ws;
  size_t off = 0;
  auto alloc = [&](size_t bytes) -> void* {
    off = (off + 255) & ~(size_t)255;
    void* p = base + off;
    off += bytes;
    return p;
  };
  int ncb = (N + (1 << CBSH) - 1) >> CBSH;

  int*    row_ptr = (int*)alloc((size_t)(N + 1) * 4);
  int*    chist   = (int*)alloc(64 * 4);
  int*    cbase   = (int*)alloc(65 * 4);
  int*    ccur    = (int*)alloc(64 * 4);
  int*    tmp     = (int*)alloc((size_t)E * 4);
  int*    recs    = (int*)alloc((size_t)E * 4);
  float*  qkv     = (float*)alloc((size_t)N * 16 * 4);
  float*  gsum    = (float*)alloc(128 * 4);
  float*  gmax    = (float*)alloc(128 * 4);
  __bf16* wqkb    = (__bf16*)alloc(2048 * 2);
  __bf16* xb      = (__bf16*)alloc((size_t)N * 128 * 2);
  __bf16* h1b     = (__bf16*)alloc((size_t)N * 128 * 2);
  __bf16* h2b     = (__bf16*)alloc((size_t)N * 128 * 2);
  __bf16* WT2     = (__bf16*)alloc((size_t)128 * 1024 * 2);
  __bf16* Y       = (__bf16*)alloc((size_t)8 * N * 128 * 2);

  // CSR build
  hipMemsetAsync(chist, 0, 64 * 4, stream);
  k_chist<<<256, 256, 0, stream>>>(dst, chist, E);
  k_cscan<<<1, 64, 0, stream>>>(chist, cbase, ccur, ncb, E);
  k_cscatter<<<(E + CSC_CH - 1) / CSC_CH, 256, 0, stream>>>(src, dst, ety, ccur, tmp, E);
  k_fsort<<<ncb, 1024, 0, stream>>>(cbase, tmp, recs, row_ptr, N, E);

  for (int layer = 0; layer < 2; ++layer) {
    const float*  W    = layer ? w1 : w0;
    const float*  qq   = layer ? q1 : q0;
    const float*  kk   = layer ? k1 : k0;
    const float*  bb   = layer ? b1 : b0;
    const __bf16* xinb = layer ? h1b : xb;
    __bf16*       hout = layer ? h2b : h1b;

    k_wprep<<<384, 256, 0, stream>>>(W, qq, kk, wqkb, WT2);
    if (layer == 0)
      k_qkv<1><<<(N + 63) / 64, 256, 0, stream>>>((const void*)x, wqkb, qkv, xb, N);
    else
      k_qkv<0><<<(N + 63) / 64, 256, 0, stream>>>((const void*)xinb, wqkb, qkv, nullptr, N);
    k_gemmY<<<(N + 127) / 128, 256, 0, stream>>>(xinb, WT2, Y, N);
    k_aggY<<<(N + 3) / 4, 256, 0, stream>>>(row_ptr, recs, qkv, Y, bb, hout, N);
  }

  hipMemsetAsync(gsum, 0, 128 * 4, stream);
  hipMemsetAsync(gmax, 0, 128 * 4, stream);
  k_pool<<<256, 256, 0, stream>>>(h2b, gsum, gmax, N);
  k_head<<<1, 256, 0, stream>>>(gsum, gmax, fc1w, fc1b, fc2w, fc2b, (float*)d_out, N);
}

// Round 11
// 258.619 us; speedup vs baseline: 5.2560x; 1.0669x over previous
//
#include <hip/hip_runtime.h>
#include <hip/hip_bf16.h>

// ---------------------------------------------------------------------------
// RGAT: 2x RGATConv (R=8, H=128) + mean/max pool + MLP head -> scalar
//
// R11 structure (fused qkv-into-gemmY; 13 dispatches):
//   CSR build: memset -> k_chist -> k_cscatter (in-block scan) -> k_fsort
//   per layer:
//     k_wprep: wqkb[16][128] = bf16(W@q|W@k)  +  WT2[h][r*128+k]
//     k_gemmY<L0>: stage A once (L0: f32 x cast in-register, no xb buffer);
//                  pass 0: qkv[N][16] = A @ wqkb^T (MFMA, 16 cols);
//                  passes r=0..7: Y[r] = A @ W[r]  (stage WT2[r] per pass)
//     k_aggY:  h[n] = relu(bias + (1/denom) sum_e w_e * Y[et][src])
//              1 wave/node; online-softmax lane-parallel; 4-edge batches
//              (16 lanes x bf16x8/edge), register acc + group shfl reduce.
//   memset -> pool (mean+max) -> head (tanh/fc1/relu/fc2/sigmoid)
//
// Record packing: rec = src | et<<17 | dlow<<20   (N < 2^17, dlow = dst&1023)
// ---------------------------------------------------------------------------

typedef __bf16 bf16x8 __attribute__((ext_vector_type(8)));
typedef __bf16 bf16x4 __attribute__((ext_vector_type(4)));
typedef __bf16 bf16x2 __attribute__((ext_vector_type(2)));
typedef float f32x4 __attribute__((ext_vector_type(4)));

#define CBSH 10                 // coarse bucket = 1024 nodes
#define CSC_CH 4096             // edges per cscatter block

// ----------------------------- CSR build -----------------------------------

__global__ __launch_bounds__(256) void k_chist(const int* __restrict__ dst, int* __restrict__ chist, int E) {
  __shared__ int lh[64];
  int t = threadIdx.x;
  if (t < 64) lh[t] = 0;
  __syncthreads();
  for (int e = blockIdx.x * 256 + t; e < E; e += gridDim.x * 256)
    atomicAdd(&lh[dst[e] >> CBSH], 1);
  __syncthreads();
  if (t < 64 && lh[t]) atomicAdd(&chist[t], lh[t]);
}

// bin edges by dst>>10; per-(block,bucket) contiguous runs; cbase computed
// in-block from chist (64-entry scan), global cursor ccur0 starts at 0.
__global__ __launch_bounds__(256) void k_cscatter(const int* __restrict__ src, const int* __restrict__ dst,
                                                  const int* __restrict__ et, const int* __restrict__ chist,
                                                  int* __restrict__ ccur0, int* __restrict__ tmp, int E) {
  __shared__ int recbuf[CSC_CH];
  __shared__ int lcnt[64], lbase[64], gbase[64], lcur[64], cb[64];
  int t = threadIdx.x;
  int base = blockIdx.x * CSC_CH;
  int cnt = E - base; if (cnt > CSC_CH) cnt = CSC_CH;
  if (t < 64) { lcnt[t] = 0; cb[t] = chist[t]; }
  __syncthreads();
  int myrec[CSC_CH / 256], mycb[CSC_CH / 256];
  int k = 0;
  for (int i = t; i < cnt; i += 256, ++k) {
    int d = dst[base + i];
    int c = d >> CBSH;
    myrec[k] = src[base + i] | (et[base + i] << 17) | ((d & ((1 << CBSH) - 1)) << 20);
    mycb[k] = c;
    atomicAdd(&lcnt[c], 1);
  }
  __syncthreads();
  if (t == 0) {
    int acc = 0, acc2 = 0;
    for (int c = 0; c < 64; ++c) {
      lbase[c] = acc; lcur[c] = acc; acc += lcnt[c];
      int h = cb[c]; cb[c] = acc2; acc2 += h;       // cb -> exclusive scan of chist
    }
  }
  __syncthreads();
  if (t < 64 && lcnt[t] > 0) gbase[t] = cb[t] + atomicAdd(&ccur0[t], lcnt[t]);
  __syncthreads();
  k = 0;
  for (int i = t; i < cnt; i += 256, ++k) {
    int p = atomicAdd(&lcur[mycb[k]], 1);
    recbuf[p] = myrec[k];
  }
  __syncthreads();
  for (int i = t; i < cnt; i += 256) {
    int lo = 0, hi = 63;
    while (lo < hi) { int mid = (lo + hi + 1) >> 1; if (lbase[mid] <= i) lo = mid; else hi = mid - 1; }
    tmp[gbase[lo] + (i - lbase[lo])] = recbuf[i];
  }
}

// block per coarse bucket: per-node histogram + scan -> row_ptr + final recs
__global__ __launch_bounds__(1024) void k_fsort(const int* __restrict__ chist, const int* __restrict__ tmp,
                                                int* __restrict__ recs, int* __restrict__ row_ptr,
                                                int N, int E) {
  __shared__ int sd[1024];
  __shared__ int ncur[1024];
  __shared__ int cbs[65];
  int cb = blockIdx.x, t = threadIdx.x;
  int n0 = cb << CBSH;
  if (t < 64) cbs[t] = chist[t];
  __syncthreads();
  if (t == 0) {
    int acc = 0;
    for (int c = 0; c < 64; ++c) { int h = cbs[c]; cbs[c] = acc; acc += h; }
    cbs[64] = acc;
  }
  sd[t] = 0;
  __syncthreads();
  int begin = cbs[cb], endd = cbs[cb + 1];
  for (int i = begin + t; i < endd; i += 1024)
    atomicAdd(&sd[(tmp[i] >> 20) & 1023], 1);
  __syncthreads();
  int myc = sd[t];
  for (int off = 1; off < 1024; off <<= 1) {
    int xv = 0; if (t >= off) xv = sd[t - off];
    __syncthreads();
    sd[t] += xv;
    __syncthreads();
  }
  int ex = sd[t] - myc;
  int node = n0 + t;
  if (node < N) row_ptr[node] = begin + ex;
  if (node == N - 1) row_ptr[N] = E;
  ncur[t] = begin + ex;
  __syncthreads();
  for (int i = begin + t; i < endd; i += 1024) {
    int rc = tmp[i];
    int p = atomicAdd(&ncur[(rc >> 20) & 1023], 1);
    recs[p] = rc & 0xFFFFF;                        // src | et<<17
  }
}

// ----------------------- merged weight precompute ----------------------------
// blocks 0..255: wqkb rows; blocks 256..383: WT2 transpose tiles.

__global__ __launch_bounds__(256) void k_wprep(const float* __restrict__ W, const float* __restrict__ q,
                                               const float* __restrict__ k, __bf16* __restrict__ wqkb,
                                               __bf16* __restrict__ WT) {
  if (blockIdx.x < 256) {
    int g = blockIdx.x * 4 + (threadIdx.x >> 6);
    int lane = threadIdx.x & 63;
    const float2* wrow = (const float2*)(W + (size_t)g * 128);
    float2 wv = wrow[lane];
    float2 qv2 = ((const float2*)q)[lane];
    float2 kv2 = ((const float2*)k)[lane];
    float aq = wv.x * qv2.x + wv.y * qv2.y;
    float ak = wv.x * kv2.x + wv.y * kv2.y;
    #pragma unroll
    for (int off = 32; off; off >>= 1) {
      aq += __shfl_xor(aq, off, 64);
      ak += __shfl_xor(ak, off, 64);
    }
    if (lane == 0) { wqkb[g] = (__bf16)aq; wqkb[1024 + g] = (__bf16)ak; }
  } else {
    __shared__ float t[32][33];
    int bb = blockIdx.x - 256;
    int r = bb >> 4;
    int rem = bb & 15;
    int k0 = (rem & 3) * 32, h0 = (rem >> 2) * 32;
    int tx = threadIdx.x & 31;
    int ty = threadIdx.x >> 5;
    #pragma unroll
    for (int i = 0; i < 4; ++i) {
      int kk = ty + i * 8;
      t[kk][tx] = W[((size_t)r * 128 + k0 + kk) * 128 + h0 + tx];
    }
    __syncthreads();
    #pragma unroll
    for (int i = 0; i < 4; ++i) {
      int hh = ty + i * 8;
      WT[(size_t)(h0 + hh) * 1024 + r * 128 + k0 + tx] = (__bf16)t[tx][hh];
    }
  }
}

// ------------------ fused transform GEMM + qkv -------------------------------
// A staged once per 128-row tile. Pass 0: qkv = A @ wqkb^T (16 cols).
// Passes r=0..7: Y[r] = A @ W[r] via WT2 rows. Stride 136 elems (2-way free).

#define ASTR 136

template <int L0>
__global__ __launch_bounds__(256) void k_gemmY(const void* __restrict__ xin,
                                               const __bf16* __restrict__ WT2,
                                               const __bf16* __restrict__ wqkb,
                                               __bf16* __restrict__ Y, float* __restrict__ qkv, int M) {
  __shared__ __bf16 As[128 * ASTR];
  __shared__ __bf16 Bs[128 * ASTR];
  int bm = blockIdx.x * 128;
  int tid = threadIdx.x;
  int w = tid >> 6, l = tid & 63;
  int srow = tid >> 1;            // 2 threads per row
  int cb8 = (tid & 1) * 8;        // 8 chunks of 8 elems per thread
  bool valid = (bm + srow) < M;

  // stage A full row (128 elems); L0 casts f32 -> bf16 in-register
  if (L0) {
    const float* gA = (const float*)xin + (size_t)(bm + srow) * 128 + cb8 * 8;
    #pragma unroll
    for (int i = 0; i < 8; ++i) {
      float4 f0 = make_float4(0.f, 0.f, 0.f, 0.f), f1 = f0;
      if (valid) { f0 = *(const float4*)(gA + i * 8); f1 = *(const float4*)(gA + i * 8 + 4); }
      bf16x8 v;
      v[0] = (__bf16)f0.x; v[1] = (__bf16)f0.y; v[2] = (__bf16)f0.z; v[3] = (__bf16)f0.w;
      v[4] = (__bf16)f1.x; v[5] = (__bf16)f1.y; v[6] = (__bf16)f1.z; v[7] = (__bf16)f1.w;
      *(bf16x8*)&As[srow * ASTR + (cb8 + i) * 8] = v;
    }
  } else {
    const bf16x8* gA = (const bf16x8*)((const __bf16*)xin + (size_t)(bm + srow) * 128);
    #pragma unroll
    for (int i = 0; i < 8; ++i) {
      bf16x8 v = valid ? gA[cb8 + i] : (bf16x8)(__bf16)0.0f;
      *(bf16x8*)&As[srow * ASTR + (cb8 + i) * 8] = v;
    }
  }
  // stage wqkb (16 rows x 128): thread tid -> row tid>>4, chunk tid&15
  {
    int qr = tid >> 4, qc = tid & 15;
    *(bf16x8*)&Bs[qr * ASTR + qc * 8] = *(const bf16x8*)(wqkb + (size_t)qr * 128 + qc * 8);
  }
  __syncthreads();

  // pass 0: qkv (16 cols)
  {
    f32x4 qacc[2];
    qacc[0] = (f32x4)0.f; qacc[1] = (f32x4)0.f;
    #pragma unroll
    for (int ks = 0; ks < 4; ++ks) {
      bf16x8 bq = *(const bf16x8*)&Bs[(l & 15) * ASTR + ks * 32 + (l >> 4) * 8];
      #pragma unroll
      for (int m2 = 0; m2 < 2; ++m2) {
        bf16x8 af = *(const bf16x8*)&As[(w * 32 + m2 * 16 + (l & 15)) * ASTR + ks * 32 + (l >> 4) * 8];
        qacc[m2] = __builtin_amdgcn_mfma_f32_16x16x32_bf16(af, bq, qacc[m2], 0, 0, 0);
      }
    }
    #pragma unroll
    for (int m2 = 0; m2 < 2; ++m2)
      #pragma unroll
      for (int j = 0; j < 4; ++j) {
        int row = w * 32 + m2 * 16 + (l >> 4) * 4 + j;
        if (bm + row < M) qkv[(size_t)(bm + row) * 16 + (l & 15)] = qacc[m2][j];
      }
  }

  for (int r = 0; r < 8; ++r) {
    __syncthreads();               // all waves done reading Bs
    {
      const bf16x8* gB = (const bf16x8*)(WT2 + (size_t)srow * 1024 + r * 128);
      #pragma unroll
      for (int i = 0; i < 8; ++i)
        *(bf16x8*)&Bs[srow * ASTR + (cb8 + i) * 8] = gB[cb8 + i];
    }
    __syncthreads();

    f32x4 acc[2][8];
    #pragma unroll
    for (int m2 = 0; m2 < 2; ++m2)
      #pragma unroll
      for (int n2 = 0; n2 < 8; ++n2) acc[m2][n2] = (f32x4)0.f;

    #pragma unroll
    for (int ks = 0; ks < 4; ++ks) {
      bf16x8 af[2], bfv[8];
      #pragma unroll
      for (int m2 = 0; m2 < 2; ++m2)
        af[m2] = *(const bf16x8*)&As[(w * 32 + m2 * 16 + (l & 15)) * ASTR + ks * 32 + (l >> 4) * 8];
      #pragma unroll
      for (int n2 = 0; n2 < 8; ++n2)
        bfv[n2] = *(const bf16x8*)&Bs[(n2 * 16 + (l & 15)) * ASTR + ks * 32 + (l >> 4) * 8];
      #pragma unroll
      for (int m2 = 0; m2 < 2; ++m2)
        #pragma unroll
        for (int n2 = 0; n2 < 8; ++n2)
          acc[m2][n2] = __builtin_amdgcn_mfma_f32_16x16x32_bf16(af[m2], bfv[n2], acc[m2][n2], 0, 0, 0);
    }

    // C/D layout: col = lane&15, row = (lane>>4)*4 + reg
    __bf16* Yr = Y + ((size_t)r * M + bm) * 128;
    #pragma unroll
    for (int m2 = 0; m2 < 2; ++m2)
      #pragma unroll
      for (int j = 0; j < 4; ++j) {
        int row = w * 32 + m2 * 16 + (l >> 4) * 4 + j;
        if (bm + row < M) {
          #pragma unroll
          for (int n2 = 0; n2 < 8; ++n2)
            Yr[(size_t)row * 128 + n2 * 16 + (l & 15)] = (__bf16)acc[m2][n2][j];
        }
      }
  }
}

// ------------------- softmax + gather aggregate (register acc) ---------------
// One wave per node. 4-edge batches: group g (16 lanes) handles edge g+4b,
// lane sub owns channels sub*8..sub*8+7. Register acc + group shfl reduce.

__global__ __launch_bounds__(256) void k_aggY(const int* __restrict__ row_ptr, const int* __restrict__ recs,
                                              const float* __restrict__ qkv, const __bf16* __restrict__ Y,
                                              const float* __restrict__ bias, __bf16* __restrict__ hout,
                                              int N) {
  int wv = threadIdx.x >> 6;
  int lane = threadIdx.x & 63;
  int n = blockIdx.x * 4 + wv;
  if (n >= N) return;
  int start = row_ptr[n], end = row_ptr[n + 1];
  const float* qvn = qkv + (size_t)n * 16;
  float denom = 0.f, m_run = -1e30f;
  int sub = lane & 15;
  int grp = lane >> 4;
  float acc[8];
  #pragma unroll
  for (int j = 0; j < 8; ++j) acc[j] = 0.f;

  for (int c0 = start; c0 < end; c0 += 64) {
    int cend = (end < c0 + 64) ? end : (c0 + 64);
    int cnt = cend - c0;
    int p = c0 + lane;
    float a = -1e30f; int rec = 0;
    if (p < cend) {
      rec = recs[p];
      int s = rec & 0x1FFFF, r = (rec >> 17) & 7;
      float t = qvn[r] + qkv[(size_t)s * 16 + 8 + r];
      a = (t >= 0.f) ? t : 0.2f * t;
    }
    float cm = a;
    #pragma unroll
    for (int off = 32; off; off >>= 1) cm = fmaxf(cm, __shfl_xor(cm, off, 64));
    if (cm > m_run) {
      if (m_run > -1e29f) {
        float scale = __expf(m_run - cm);
        denom *= scale;
        #pragma unroll
        for (int j = 0; j < 8; ++j) acc[j] *= scale;
      }
      m_run = cm;
    }
    float wgt = (p < cend) ? __expf(a - m_run) : 0.f;   // 0 on pad lanes
    float ws = wgt;
    #pragma unroll
    for (int off = 32; off; off >>= 1) ws += __shfl_xor(ws, off, 64);
    denom += ws;
    int wbits = __float_as_int(wgt);

    int nbatch = (cnt + 3) >> 2;
    #pragma unroll 2
    for (int b = 0; b < nbatch; ++b) {
      int idx = grp * 4 + b * 16;                         // -> lane grp+4b
      int rg = __builtin_amdgcn_ds_bpermute(idx, rec);
      int wg = __builtin_amdgcn_ds_bpermute(idx, wbits);
      float fw = __int_as_float(wg);
      int s_ = rg & 0x1FFFF;
      int r_ = (rg >> 17) & 7;
      bf16x8 xv = *(const bf16x8*)(Y + ((size_t)r_ * N + s_) * 128 + sub * 8);
      #pragma unroll
      for (int j = 0; j < 8; ++j) acc[j] += fw * (float)xv[j];
    }
  }

  // reduce the 4 group partials (lanes differing in bits 4,5)
  #pragma unroll
  for (int j = 0; j < 8; ++j) {
    acc[j] += __shfl_xor(acc[j], 16, 64);
    acc[j] += __shfl_xor(acc[j], 32, 64);
  }
  float inv = 1.f / (denom + 1e-16f);
  if (grp == 0) {
    float4 b0 = *(const float4*)(bias + sub * 8);
    float4 b1 = *(const float4*)(bias + sub * 8 + 4);
    float bb[8] = {b0.x, b0.y, b0.z, b0.w, b1.x, b1.y, b1.z, b1.w};
    bf16x8 o;
    #pragma unroll
    for (int j = 0; j < 8; ++j) o[j] = (__bf16)fmaxf(acc[j] * inv + bb[j], 0.f);
    *(bf16x8*)(hout + (size_t)n * 128 + sub * 8) = o;
  }
}

// ------------------------------- pool + head ---------------------------------

__global__ __launch_bounds__(256) void k_pool(const __bf16* __restrict__ h, float* __restrict__ gsum,
                                              float* __restrict__ gmax, int N) {
  int c2 = threadIdx.x & 63;
  int grp = threadIdx.x >> 6;
  float s0 = 0.f, s1 = 0.f, m0 = 0.f, m1 = 0.f;
  for (int n = blockIdx.x * 4 + grp; n < N; n += gridDim.x * 4) {
    bf16x2 v = ((const bf16x2*)(h + (size_t)n * 128))[c2];
    float v0 = (float)v.x, v1 = (float)v.y;
    s0 += v0; s1 += v1;
    m0 = fmaxf(m0, v0); m1 = fmaxf(m1, v1);
  }
  __shared__ float ss0[256], ss1[256], sm0[256], sm1[256];
  ss0[threadIdx.x] = s0; ss1[threadIdx.x] = s1;
  sm0[threadIdx.x] = m0; sm1[threadIdx.x] = m1;
  __syncthreads();
  if (grp == 0) {
    #pragma unroll
    for (int g = 1; g < 4; ++g) {
      s0 += ss0[g * 64 + c2]; s1 += ss1[g * 64 + c2];
      m0 = fmaxf(m0, sm0[g * 64 + c2]); m1 = fmaxf(m1, sm1[g * 64 + c2]);
    }
    atomicAdd(&gsum[2 * c2 + 0], s0);
    atomicAdd(&gsum[2 * c2 + 1], s1);
    atomicMax((int*)gmax + 2 * c2 + 0, __float_as_int(m0));
    atomicMax((int*)gmax + 2 * c2 + 1, __float_as_int(m1));
  }
}

__global__ void k_head(const float* __restrict__ gsum, const float* __restrict__ gmax,
                       const float* __restrict__ fc1w, const float* __restrict__ fc1b,
                       const float* __restrict__ fc2w, const float* __restrict__ fc2b,
                       float* __restrict__ out, int N) {
  __shared__ float g[256];
  __shared__ float red[128];
  int t = threadIdx.x;
  if (t < 128) g[t] = tanhf(gsum[t] / (float)N);
  else g[t] = tanhf(gmax[t - 128]);
  __syncthreads();
  float r1 = 0.f;
  if (t < 128) {
    float a = fc1b[t];
    for (int i = 0; i < 256; i++) a += g[i] * fc1w[i * 128 + t];
    r1 = a > 0.f ? a : 0.f;
    red[t] = r1 * fc2w[t];
  }
  __syncthreads();
  for (int s = 64; s > 0; s >>= 1) {
    if (t < s) red[t] += red[t + s];
    __syncthreads();
  }
  if (t == 0) {
    float o = red[0] + fc2b[0];
    out[0] = 1.f / (1.f + __expf(-o));
  }
}

// --------------------------------- launch ------------------------------------

extern "C" void kernel_launch(void* const* d_in, const int* in_sizes, int n_in,
                              void* d_out, int out_size, void* d_ws, size_t ws_size,
                              hipStream_t stream) {
  const float* x    = (const float*)d_in[0];
  const int*   ei   = (const int*)d_in[1];
  const int*   ety  = (const int*)d_in[2];
  const float* w0   = (const float*)d_in[3];
  const float* q0   = (const float*)d_in[4];
  const float* k0   = (const float*)d_in[5];
  const float* b0   = (const float*)d_in[6];
  const float* w1   = (const float*)d_in[7];
  const float* q1   = (const float*)d_in[8];
  const float* k1   = (const float*)d_in[9];
  const float* b1   = (const float*)d_in[10];
  const float* fc1w = (const float*)d_in[11];
  const float* fc1b = (const float*)d_in[12];
  const float* fc2w = (const float*)d_in[13];
  const float* fc2b = (const float*)d_in[14];
  int N = in_sizes[0] / 128;
  int E = in_sizes[2];
  const int* src = ei;
  const int* dst = ei + E;

  char* base = (char*)d_ws;
  size_t off = 0;
  auto alloc = [&](size_t bytes) -> void* {
    off = (off + 255) & ~(size_t)255;
    void* p = base + off;
    off += bytes;
    return p;
  };
  int ncb = (N + (1 << CBSH) - 1) >> CBSH;

  int*    row_ptr = (int*)alloc((size_t)(N + 1) * 4);
  int*    csrctr  = (int*)alloc(128 * 4);          // chist[64] + ccur0[64]
  int*    chist   = csrctr;
  int*    ccur0   = csrctr + 64;
  int*    tmp     = (int*)alloc((size_t)E * 4);
  int*    recs    = (int*)alloc((size_t)E * 4);
  float*  qkv     = (float*)alloc((size_t)N * 16 * 4);
  float*  gpool   = (float*)alloc(256 * 4);        // gsum[128] + gmax[128]
  float*  gsum    = gpool;
  float*  gmax    = gpool + 128;
  __bf16* wqkb    = (__bf16*)alloc(2048 * 2);
  __bf16* h1b     = (__bf16*)alloc((size_t)N * 128 * 2);
  __bf16* h2b     = (__bf16*)alloc((size_t)N * 128 * 2);
  __bf16* WT2     = (__bf16*)alloc((size_t)128 * 1024 * 2);
  __bf16* Y       = (__bf16*)alloc((size_t)8 * N * 128 * 2);

  // CSR build (3 kernels + 1 memset)
  hipMemsetAsync(csrctr, 0, 128 * 4, stream);
  k_chist<<<256, 256, 0, stream>>>(dst, chist, E);
  k_cscatter<<<(E + CSC_CH - 1) / CSC_CH, 256, 0, stream>>>(src, dst, ety, chist, ccur0, tmp, E);
  k_fsort<<<ncb, 1024, 0, stream>>>(chist, tmp, recs, row_ptr, N, E);

  for (int layer = 0; layer < 2; ++layer) {
    const float*  W    = layer ? w1 : w0;
    const float*  qq   = layer ? q1 : q0;
    const float*  kk   = layer ? k1 : k0;
    const float*  bb   = layer ? b1 : b0;
    __bf16*       hout = layer ? h2b : h1b;

    k_wprep<<<384, 256, 0, stream>>>(W, qq, kk, wqkb, WT2);
    if (layer == 0)
      k_gemmY<1><<<(N + 127) / 128, 256, 0, stream>>>((const void*)x, WT2, wqkb, Y, qkv, N);
    else
      k_gemmY<0><<<(N + 127) / 128, 256, 0, stream>>>((const void*)h1b, WT2, wqkb, Y, qkv, N);
    k_aggY<<<(N + 3) / 4, 256, 0, stream>>>(row_ptr, recs, qkv, Y, bb, hout, N);
  }

  hipMemsetAsync(gpool, 0, 256 * 4, stream);
  k_pool<<<256, 256, 0, stream>>>(h2b, gsum, gmax, N);
  k_head<<<1, 256, 0, stream>>>(gsum, gmax, fc1w, fc1b, fc2w, fc2b, (float*)d_out, N);
}

// Round 12
// 242.297 us; speedup vs baseline: 5.6100x; 1.0674x over previous
//
#include <hip/hip_runtime.h>
#include <hip/hip_bf16.h>

// ---------------------------------------------------------------------------
// RGAT: 2x RGATConv (R=8, H=128) + mean/max pool + MLP head -> scalar
//
// R12 structure (fp8 value path; 11 dispatches):
//   CSR build: memset -> k_chist -> k_cscatter (in-block scan) -> k_fsort
//   k_wprep (ONE dispatch, both layers): wqkb[l][16][128], WT2[l][h][r*128+k]
//   per layer:
//     k_gemmY<L0>: stage A once; pass 0: qkv[N][16] = A @ wqkb^T (MFMA);
//                  passes r=0..7: Y[r] = A @ W[r], stored FP8 E4M3
//     k_aggY:  h[n] = relu(bias + (1/denom) sum_e w_e * Y[et][src])
//              1 wave/node; online-softmax lane-parallel (f32 logits -- only
//              the value path is fp8); 4-edge batches (16 lanes x 8B fp8 per
//              edge, 1 dwordx2 insn = 4 rows), cvt_pk_f32_fp8 decode,
//              register acc + group shfl reduce.
//   pool (mean+max) -> head (tanh/fc1/relu/fc2/sigmoid)
//
// Record packing: rec = src | et<<17 | dlow<<20   (N < 2^17, dlow = dst&1023)
// ---------------------------------------------------------------------------

typedef __bf16 bf16x8 __attribute__((ext_vector_type(8)));
typedef __bf16 bf16x4 __attribute__((ext_vector_type(4)));
typedef __bf16 bf16x2 __attribute__((ext_vector_type(2)));
typedef float f32x4 __attribute__((ext_vector_type(4)));
typedef float f32x2 __attribute__((ext_vector_type(2)));

#define CBSH 10                 // coarse bucket = 1024 nodes
#define CSC_CH 4096             // edges per cscatter block

// ----------------------------- CSR build -----------------------------------

__global__ __launch_bounds__(256) void k_chist(const int* __restrict__ dst, int* __restrict__ chist, int E) {
  __shared__ int lh[64];
  int t = threadIdx.x;
  if (t < 64) lh[t] = 0;
  __syncthreads();
  for (int e = blockIdx.x * 256 + t; e < E; e += gridDim.x * 256)
    atomicAdd(&lh[dst[e] >> CBSH], 1);
  __syncthreads();
  if (t < 64 && lh[t]) atomicAdd(&chist[t], lh[t]);
}

__global__ __launch_bounds__(256) void k_cscatter(const int* __restrict__ src, const int* __restrict__ dst,
                                                  const int* __restrict__ et, const int* __restrict__ chist,
                                                  int* __restrict__ ccur0, int* __restrict__ tmp, int E) {
  __shared__ int recbuf[CSC_CH];
  __shared__ int lcnt[64], lbase[64], gbase[64], lcur[64], cb[64];
  int t = threadIdx.x;
  int base = blockIdx.x * CSC_CH;
  int cnt = E - base; if (cnt > CSC_CH) cnt = CSC_CH;
  if (t < 64) { lcnt[t] = 0; cb[t] = chist[t]; }
  __syncthreads();
  int myrec[CSC_CH / 256], mycb[CSC_CH / 256];
  int k = 0;
  for (int i = t; i < cnt; i += 256, ++k) {
    int d = dst[base + i];
    int c = d >> CBSH;
    myrec[k] = src[base + i] | (et[base + i] << 17) | ((d & ((1 << CBSH) - 1)) << 20);
    mycb[k] = c;
    atomicAdd(&lcnt[c], 1);
  }
  __syncthreads();
  if (t == 0) {
    int acc = 0, acc2 = 0;
    for (int c = 0; c < 64; ++c) {
      lbase[c] = acc; lcur[c] = acc; acc += lcnt[c];
      int h = cb[c]; cb[c] = acc2; acc2 += h;       // cb -> exclusive scan of chist
    }
  }
  __syncthreads();
  if (t < 64 && lcnt[t] > 0) gbase[t] = cb[t] + atomicAdd(&ccur0[t], lcnt[t]);
  __syncthreads();
  k = 0;
  for (int i = t; i < cnt; i += 256, ++k) {
    int p = atomicAdd(&lcur[mycb[k]], 1);
    recbuf[p] = myrec[k];
  }
  __syncthreads();
  for (int i = t; i < cnt; i += 256) {
    int lo = 0, hi = 63;
    while (lo < hi) { int mid = (lo + hi + 1) >> 1; if (lbase[mid] <= i) lo = mid; else hi = mid - 1; }
    tmp[gbase[lo] + (i - lbase[lo])] = recbuf[i];
  }
}

__global__ __launch_bounds__(1024) void k_fsort(const int* __restrict__ chist, const int* __restrict__ tmp,
                                                int* __restrict__ recs, int* __restrict__ row_ptr,
                                                int N, int E) {
  __shared__ int sd[1024];
  __shared__ int ncur[1024];
  __shared__ int cbs[65];
  int cb = blockIdx.x, t = threadIdx.x;
  int n0 = cb << CBSH;
  if (t < 64) cbs[t] = chist[t];
  __syncthreads();
  if (t == 0) {
    int acc = 0;
    for (int c = 0; c < 64; ++c) { int h = cbs[c]; cbs[c] = acc; acc += h; }
    cbs[64] = acc;
  }
  sd[t] = 0;
  __syncthreads();
  int begin = cbs[cb], endd = cbs[cb + 1];
  for (int i = begin + t; i < endd; i += 1024)
    atomicAdd(&sd[(tmp[i] >> 20) & 1023], 1);
  __syncthreads();
  int myc = sd[t];
  for (int off = 1; off < 1024; off <<= 1) {
    int xv = 0; if (t >= off) xv = sd[t - off];
    __syncthreads();
    sd[t] += xv;
    __syncthreads();
  }
  int ex = sd[t] - myc;
  int node = n0 + t;
  if (node < N) row_ptr[node] = begin + ex;
  if (node == N - 1) row_ptr[N] = E;
  ncur[t] = begin + ex;
  __syncthreads();
  for (int i = begin + t; i < endd; i += 1024) {
    int rc = tmp[i];
    int p = atomicAdd(&ncur[(rc >> 20) & 1023], 1);
    recs[p] = rc & 0xFFFFF;                        // src | et<<17
  }
}

// ----------------------- merged weight precompute (both layers) --------------
// per layer: blocks 0..255 wqkb rows; 256..383 WT2 transpose tiles.

__global__ __launch_bounds__(256) void k_wprep(const float* __restrict__ w0, const float* __restrict__ q0,
                                               const float* __restrict__ k0, const float* __restrict__ w1,
                                               const float* __restrict__ q1, const float* __restrict__ k1,
                                               __bf16* __restrict__ wqkb, __bf16* __restrict__ WT) {
  int layer = blockIdx.x >> 9;        // >=384? use /384 via compare below
  int bx = blockIdx.x;
  if (bx >= 384) { layer = 1; bx -= 384; } else layer = 0;
  const float* W = layer ? w1 : w0;
  const float* q = layer ? q1 : q0;
  const float* k = layer ? k1 : k0;
  __bf16* wq = wqkb + layer * 2048;
  __bf16* WTl = WT + (size_t)layer * 131072;
  if (bx < 256) {
    int g = bx * 4 + (threadIdx.x >> 6);
    int lane = threadIdx.x & 63;
    const float2* wrow = (const float2*)(W + (size_t)g * 128);
    float2 wv = wrow[lane];
    float2 qv2 = ((const float2*)q)[lane];
    float2 kv2 = ((const float2*)k)[lane];
    float aq = wv.x * qv2.x + wv.y * qv2.y;
    float ak = wv.x * kv2.x + wv.y * kv2.y;
    #pragma unroll
    for (int off = 32; off; off >>= 1) {
      aq += __shfl_xor(aq, off, 64);
      ak += __shfl_xor(ak, off, 64);
    }
    if (lane == 0) { wq[g] = (__bf16)aq; wq[1024 + g] = (__bf16)ak; }
  } else {
    __shared__ float t[32][33];
    int bb = bx - 256;
    int r = bb >> 4;
    int rem = bb & 15;
    int kk0 = (rem & 3) * 32, h0 = (rem >> 2) * 32;
    int tx = threadIdx.x & 31;
    int ty = threadIdx.x >> 5;
    #pragma unroll
    for (int i = 0; i < 4; ++i) {
      int kk = ty + i * 8;
      t[kk][tx] = W[((size_t)r * 128 + kk0 + kk) * 128 + h0 + tx];
    }
    __syncthreads();
    #pragma unroll
    for (int i = 0; i < 4; ++i) {
      int hh = ty + i * 8;
      WTl[(size_t)(h0 + hh) * 1024 + r * 128 + kk0 + tx] = (__bf16)t[tx][hh];
    }
  }
}

// ------------------ fused transform GEMM + qkv (fp8 Y out) -------------------

#define ASTR 136

template <int L0>
__global__ __launch_bounds__(256) void k_gemmY(const void* __restrict__ xin,
                                               const __bf16* __restrict__ WT2,
                                               const __bf16* __restrict__ wqkb,
                                               unsigned char* __restrict__ Y, float* __restrict__ qkv, int M) {
  __shared__ __bf16 As[128 * ASTR];
  __shared__ __bf16 Bs[128 * ASTR];
  int bm = blockIdx.x * 128;
  int tid = threadIdx.x;
  int w = tid >> 6, l = tid & 63;
  int srow = tid >> 1;
  int cb8 = (tid & 1) * 8;
  bool valid = (bm + srow) < M;

  if (L0) {
    const float* gA = (const float*)xin + (size_t)(bm + srow) * 128 + cb8 * 8;
    #pragma unroll
    for (int i = 0; i < 8; ++i) {
      float4 f0 = make_float4(0.f, 0.f, 0.f, 0.f), f1 = f0;
      if (valid) { f0 = *(const float4*)(gA + i * 8); f1 = *(const float4*)(gA + i * 8 + 4); }
      bf16x8 v;
      v[0] = (__bf16)f0.x; v[1] = (__bf16)f0.y; v[2] = (__bf16)f0.z; v[3] = (__bf16)f0.w;
      v[4] = (__bf16)f1.x; v[5] = (__bf16)f1.y; v[6] = (__bf16)f1.z; v[7] = (__bf16)f1.w;
      *(bf16x8*)&As[srow * ASTR + (cb8 + i) * 8] = v;
    }
  } else {
    const bf16x8* gA = (const bf16x8*)((const __bf16*)xin + (size_t)(bm + srow) * 128);
    #pragma unroll
    for (int i = 0; i < 8; ++i) {
      bf16x8 v = valid ? gA[cb8 + i] : (bf16x8)(__bf16)0.0f;
      *(bf16x8*)&As[srow * ASTR + (cb8 + i) * 8] = v;
    }
  }
  {
    int qr = tid >> 4, qc = tid & 15;
    *(bf16x8*)&Bs[qr * ASTR + qc * 8] = *(const bf16x8*)(wqkb + (size_t)qr * 128 + qc * 8);
  }
  __syncthreads();

  // pass 0: qkv (16 cols)
  {
    f32x4 qacc[2];
    qacc[0] = (f32x4)0.f; qacc[1] = (f32x4)0.f;
    #pragma unroll
    for (int ks = 0; ks < 4; ++ks) {
      bf16x8 bq = *(const bf16x8*)&Bs[(l & 15) * ASTR + ks * 32 + (l >> 4) * 8];
      #pragma unroll
      for (int m2 = 0; m2 < 2; ++m2) {
        bf16x8 af = *(const bf16x8*)&As[(w * 32 + m2 * 16 + (l & 15)) * ASTR + ks * 32 + (l >> 4) * 8];
        qacc[m2] = __builtin_amdgcn_mfma_f32_16x16x32_bf16(af, bq, qacc[m2], 0, 0, 0);
      }
    }
    #pragma unroll
    for (int m2 = 0; m2 < 2; ++m2)
      #pragma unroll
      for (int j = 0; j < 4; ++j) {
        int row = w * 32 + m2 * 16 + (l >> 4) * 4 + j;
        if (bm + row < M) qkv[(size_t)(bm + row) * 16 + (l & 15)] = qacc[m2][j];
      }
  }

  for (int r = 0; r < 8; ++r) {
    __syncthreads();
    {
      const bf16x8* gB = (const bf16x8*)(WT2 + (size_t)srow * 1024 + r * 128);
      #pragma unroll
      for (int i = 0; i < 8; ++i)
        *(bf16x8*)&Bs[srow * ASTR + (cb8 + i) * 8] = gB[cb8 + i];
    }
    __syncthreads();

    f32x4 acc[2][8];
    #pragma unroll
    for (int m2 = 0; m2 < 2; ++m2)
      #pragma unroll
      for (int n2 = 0; n2 < 8; ++n2) acc[m2][n2] = (f32x4)0.f;

    #pragma unroll
    for (int ks = 0; ks < 4; ++ks) {
      bf16x8 af[2], bfv[8];
      #pragma unroll
      for (int m2 = 0; m2 < 2; ++m2)
        af[m2] = *(const bf16x8*)&As[(w * 32 + m2 * 16 + (l & 15)) * ASTR + ks * 32 + (l >> 4) * 8];
      #pragma unroll
      for (int n2 = 0; n2 < 8; ++n2)
        bfv[n2] = *(const bf16x8*)&Bs[(n2 * 16 + (l & 15)) * ASTR + ks * 32 + (l >> 4) * 8];
      #pragma unroll
      for (int m2 = 0; m2 < 2; ++m2)
        #pragma unroll
        for (int n2 = 0; n2 < 8; ++n2)
          acc[m2][n2] = __builtin_amdgcn_mfma_f32_16x16x32_bf16(af[m2], bfv[n2], acc[m2][n2], 0, 0, 0);
    }

    // C/D layout: col = lane&15, row = (lane>>4)*4 + reg; store fp8 e4m3
    unsigned char* Yr = Y + ((size_t)r * M + bm) * 128;
    #pragma unroll
    for (int m2 = 0; m2 < 2; ++m2)
      #pragma unroll
      for (int j = 0; j < 4; ++j) {
        int row = w * 32 + m2 * 16 + (l >> 4) * 4 + j;
        if (bm + row < M) {
          #pragma unroll
          for (int n2 = 0; n2 < 8; ++n2) {
            float v = acc[m2][n2][j];
            int pk = __builtin_amdgcn_cvt_pk_fp8_f32(v, v, 0, false);
            Yr[(size_t)row * 128 + n2 * 16 + (l & 15)] = (unsigned char)(pk & 0xFF);
          }
        }
      }
  }
}

// ------------------- softmax + gather aggregate (fp8 value path) -------------
// One wave per node. 4-edge batches: group g (16 lanes) handles edge g+4b,
// lane sub owns channels sub*8..sub*8+7 (8 fp8 = dwordx2 gather).

__global__ __launch_bounds__(256) void k_aggY(const int* __restrict__ row_ptr, const int* __restrict__ recs,
                                              const float* __restrict__ qkv, const unsigned char* __restrict__ Y,
                                              const float* __restrict__ bias, __bf16* __restrict__ hout,
                                              int N) {
  int wv = threadIdx.x >> 6;
  int lane = threadIdx.x & 63;
  int n = blockIdx.x * 4 + wv;
  if (n >= N) return;
  int start = row_ptr[n], end = row_ptr[n + 1];
  const float* qvn = qkv + (size_t)n * 16;
  float denom = 0.f, m_run = -1e30f;
  int sub = lane & 15;
  int grp = lane >> 4;
  float acc[8];
  #pragma unroll
  for (int j = 0; j < 8; ++j) acc[j] = 0.f;

  for (int c0 = start; c0 < end; c0 += 64) {
    int cend = (end < c0 + 64) ? end : (c0 + 64);
    int cnt = cend - c0;
    int p = c0 + lane;
    float a = -1e30f; int rec = 0;
    if (p < cend) {
      rec = recs[p];
      int s = rec & 0x1FFFF, r = (rec >> 17) & 7;
      float t = qvn[r] + qkv[(size_t)s * 16 + 8 + r];
      a = (t >= 0.f) ? t : 0.2f * t;
    }
    float cm = a;
    #pragma unroll
    for (int off = 32; off; off >>= 1) cm = fmaxf(cm, __shfl_xor(cm, off, 64));
    if (cm > m_run) {
      if (m_run > -1e29f) {
        float scale = __expf(m_run - cm);
        denom *= scale;
        #pragma unroll
        for (int j = 0; j < 8; ++j) acc[j] *= scale;
      }
      m_run = cm;
    }
    float wgt = (p < cend) ? __expf(a - m_run) : 0.f;   // 0 on pad lanes
    float ws = wgt;
    #pragma unroll
    for (int off = 32; off; off >>= 1) ws += __shfl_xor(ws, off, 64);
    denom += ws;
    int wbits = __float_as_int(wgt);

    int nbatch = (cnt + 3) >> 2;
    #pragma unroll 2
    for (int b = 0; b < nbatch; ++b) {
      int idx = grp * 4 + b * 16;                         // -> lane grp+4b
      int rg = __builtin_amdgcn_ds_bpermute(idx, rec);
      int wg = __builtin_amdgcn_ds_bpermute(idx, wbits);
      float fw = __int_as_float(wg);
      int s_ = rg & 0x1FFFF;
      int r_ = (rg >> 17) & 7;
      int2 xv = *(const int2*)(Y + (((size_t)r_ * N + s_) << 7) + sub * 8);
      f32x2 f01 = __builtin_amdgcn_cvt_pk_f32_fp8(xv.x, false);
      f32x2 f23 = __builtin_amdgcn_cvt_pk_f32_fp8(xv.x, true);
      f32x2 f45 = __builtin_amdgcn_cvt_pk_f32_fp8(xv.y, false);
      f32x2 f67 = __builtin_amdgcn_cvt_pk_f32_fp8(xv.y, true);
      acc[0] += fw * f01[0]; acc[1] += fw * f01[1];
      acc[2] += fw * f23[0]; acc[3] += fw * f23[1];
      acc[4] += fw * f45[0]; acc[5] += fw * f45[1];
      acc[6] += fw * f67[0]; acc[7] += fw * f67[1];
    }
  }

  // reduce the 4 group partials (lanes differing in bits 4,5)
  #pragma unroll
  for (int j = 0; j < 8; ++j) {
    acc[j] += __shfl_xor(acc[j], 16, 64);
    acc[j] += __shfl_xor(acc[j], 32, 64);
  }
  float inv = 1.f / (denom + 1e-16f);
  if (grp == 0) {
    float4 b0 = *(const float4*)(bias + sub * 8);
    float4 b1 = *(const float4*)(bias + sub * 8 + 4);
    float bb[8] = {b0.x, b0.y, b0.z, b0.w, b1.x, b1.y, b1.z, b1.w};
    bf16x8 o;
    #pragma unroll
    for (int j = 0; j < 8; ++j) o[j] = (__bf16)fmaxf(acc[j] * inv + bb[j], 0.f);
    *(bf16x8*)(hout + (size_t)n * 128 + sub * 8) = o;
  }
}

// ------------------------------- pool + head ---------------------------------

__global__ __launch_bounds__(256) void k_pool(const __bf16* __restrict__ h, float* __restrict__ gsum,
                                              float* __restrict__ gmax, int N) {
  int c2 = threadIdx.x & 63;
  int grp = threadIdx.x >> 6;
  float s0 = 0.f, s1 = 0.f, m0 = 0.f, m1 = 0.f;
  for (int n = blockIdx.x * 4 + grp; n < N; n += gridDim.x * 4) {
    bf16x2 v = ((const bf16x2*)(h + (size_t)n * 128))[c2];
    float v0 = (float)v.x, v1 = (float)v.y;
    s0 += v0; s1 += v1;
    m0 = fmaxf(m0, v0); m1 = fmaxf(m1, v1);
  }
  __shared__ float ss0[256], ss1[256], sm0[256], sm1[256];
  ss0[threadIdx.x] = s0; ss1[threadIdx.x] = s1;
  sm0[threadIdx.x] = m0; sm1[threadIdx.x] = m1;
  __syncthreads();
  if (grp == 0) {
    #pragma unroll
    for (int g = 1; g < 4; ++g) {
      s0 += ss0[g * 64 + c2]; s1 += ss1[g * 64 + c2];
      m0 = fmaxf(m0, sm0[g * 64 + c2]); m1 = fmaxf(m1, sm1[g * 64 + c2]);
    }
    atomicAdd(&gsum[2 * c2 + 0], s0);
    atomicAdd(&gsum[2 * c2 + 1], s1);
    atomicMax((int*)gmax + 2 * c2 + 0, __float_as_int(m0));
    atomicMax((int*)gmax + 2 * c2 + 1, __float_as_int(m1));
  }
}

__global__ void k_head(const float* __restrict__ gsum, const float* __restrict__ gmax,
                       const float* __restrict__ fc1w, const float* __restrict__ fc1b,
                       const float* __restrict__ fc2w, const float* __restrict__ fc2b,
                       float* __restrict__ out, int N) {
  __shared__ float g[256];
  __shared__ float red[128];
  int t = threadIdx.x;
  if (t < 128) g[t] = tanhf(gsum[t] / (float)N);
  else g[t] = tanhf(gmax[t - 128]);
  __syncthreads();
  float r1 = 0.f;
  if (t < 128) {
    float a = fc1b[t];
    for (int i = 0; i < 256; i++) a += g[i] * fc1w[i * 128 + t];
    r1 = a > 0.f ? a : 0.f;
    red[t] = r1 * fc2w[t];
  }
  __syncthreads();
  for (int s = 64; s > 0; s >>= 1) {
    if (t < s) red[t] += red[t + s];
    __syncthreads();
  }
  if (t == 0) {
    float o = red[0] + fc2b[0];
    out[0] = 1.f / (1.f + __expf(-o));
  }
}

// --------------------------------- launch ------------------------------------

extern "C" void kernel_launch(void* const* d_in, const int* in_sizes, int n_in,
                              void* d_out, int out_size, void* d_ws, size_t ws_size,
                              hipStream_t stream) {
  const float* x    = (const float*)d_in[0];
  const int*   ei   = (const int*)d_in[1];
  const int*   ety  = (const int*)d_in[2];
  const float* w0   = (const float*)d_in[3];
  const float* q0   = (const float*)d_in[4];
  const float* k0   = (const float*)d_in[5];
  const float* b0   = (const float*)d_in[6];
  const float* w1   = (const float*)d_in[7];
  const float* q1   = (const float*)d_in[8];
  const float* k1   = (const float*)d_in[9];
  const float* b1   = (const float*)d_in[10];
  const float* fc1w = (const float*)d_in[11];
  const float* fc1b = (const float*)d_in[12];
  const float* fc2w = (const float*)d_in[13];
  const float* fc2b = (const float*)d_in[14];
  int N = in_sizes[0] / 128;
  int E = in_sizes[2];
  const int* src = ei;
  const int* dst = ei + E;

  char* base = (char*)d_ws;
  size_t off = 0;
  auto alloc = [&](size_t bytes) -> void* {
    off = (off + 255) & ~(size_t)255;
    void* p = base + off;
    off += bytes;
    return p;
  };
  int ncb = (N + (1 << CBSH) - 1) >> CBSH;

  int*    row_ptr = (int*)alloc((size_t)(N + 1) * 4);
  int*    ctrl    = (int*)alloc(384 * 4);          // chist[64]+ccur0[64]+gpool[256]
  int*    chist   = ctrl;
  int*    ccur0   = ctrl + 64;
  float*  gpool   = (float*)(ctrl + 128);
  float*  gsum    = gpool;
  float*  gmax    = gpool + 128;
  int*    tmp     = (int*)alloc((size_t)E * 4);
  int*    recs    = (int*)alloc((size_t)E * 4);
  float*  qkv     = (float*)alloc((size_t)N * 16 * 4);
  __bf16* wqkb    = (__bf16*)alloc(2 * 2048 * 2);
  __bf16* h1b     = (__bf16*)alloc((size_t)N * 128 * 2);
  __bf16* h2b     = (__bf16*)alloc((size_t)N * 128 * 2);
  __bf16* WT2     = (__bf16*)alloc((size_t)2 * 131072 * 2);
  unsigned char* Y = (unsigned char*)alloc((size_t)8 * N * 128);

  // CSR build + control init (1 memset, 3 kernels)
  hipMemsetAsync(ctrl, 0, 384 * 4, stream);
  k_chist<<<256, 256, 0, stream>>>(dst, chist, E);
  k_cscatter<<<(E + CSC_CH - 1) / CSC_CH, 256, 0, stream>>>(src, dst, ety, chist, ccur0, tmp, E);
  k_fsort<<<ncb, 1024, 0, stream>>>(chist, tmp, recs, row_ptr, N, E);

  // both layers' weight prep in one dispatch
  k_wprep<<<768, 256, 0, stream>>>(w0, q0, k0, w1, q1, k1, wqkb, WT2);

  for (int layer = 0; layer < 2; ++layer) {
    const float* bb   = layer ? b1 : b0;
    __bf16*      hout = layer ? h2b : h1b;
    if (layer == 0)
      k_gemmY<1><<<(N + 127) / 128, 256, 0, stream>>>((const void*)x, WT2, wqkb, Y, qkv, N);
    else
      k_gemmY<0><<<(N + 127) / 128, 256, 0, stream>>>((const void*)h1b, WT2 + 131072, wqkb + 2048, Y, qkv, N);
    k_aggY<<<(N + 3) / 4, 256, 0, stream>>>(row_ptr, recs, qkv, Y, bb, hout, N);
  }

  k_pool<<<256, 256, 0, stream>>>(h2b, gsum, gmax, N);
  k_head<<<1, 256, 0, stream>>>(gsum, gmax, fc1w, fc1b, fc2w, fc2b, (float*)d_out, N);
}